// Round 14
// baseline (232.103 us; speedup 1.0000x reference)
//
#include <hip/hip_runtime.h>
#include <hip/hip_bf16.h>
#include <math.h>

// SelectiveStateSpaceMixer — round 14: split BK. gemm_in BK=64 (measured best:
// 77.6us, 0 conflicts), gemm_out BK=128 (kept from R13's total win). Rest = R13.
// ws layout (bytes):
//   xzb    bf16[8192][4096]  67108864 @ 0
//   xb     bf16[8192][1024]  16777216 @ 67108864
//   xact   bf16[8192][2048]  33554432 @ 83886080
//   hb     bf16[8192][2048]  33554432 @ 117440512
//   dtbcT  f32 [192][8192]    6291456 @ 150994944
//   ybuf   f32 [8192][64]     2097152 @ 157286400
//   ynb    bf16[8192][64]     1048576 @ 159383552
//   WinT   bf16[4096][1024]   8388608 @ 160432128
//   WoutT  bf16[1024][2048]   4194304 @ 168820736
//   WdtbcT bf16[192][2048]     786432 @ 173015040
//   WsiT   bf16[2048][64]      262144 @ 173801472   end 174063616

namespace {

typedef __bf16 bf16x8 __attribute__((ext_vector_type(8)));
typedef float  f32x4  __attribute__((ext_vector_type(4)));
typedef unsigned short u16;

constexpr int kSeq = 4096;

__device__ __forceinline__ float sigmoid_f(float x) { return 1.0f / (1.0f + expf(-x)); }
__device__ __forceinline__ u16   f2bf(float f) { __bf16 h = (__bf16)f; return __builtin_bit_cast(u16, h); }
__device__ __forceinline__ float bf2f(u16 u)   { return (float)__builtin_bit_cast(__bf16, u); }

// async global->LDS, 16B per lane (dest = wave-uniform base + lane*16)
__device__ __forceinline__ void gll16(const u16* g, u16* l) {
    __builtin_amdgcn_global_load_lds(
        (const __attribute__((address_space(1))) unsigned int*)g,
        (__attribute__((address_space(3))) unsigned int*)l,
        16, 0, 0);
}

// bijective XCD-aware block swizzle (m204)
__device__ __forceinline__ int xcd_swizzle(int lin, int nwg) {
    const int q = nwg >> 3, r = nwg & 7;
    const int xcd = lin & 7, idx = lin >> 3;
    return (xcd < r ? xcd * (q + 1) : r * (q + 1) + (xcd - r) * q) + idx;
}

// ---------- 32x32 tile transpose body: fp32 [R][C] -> bf16 [C][R] ----------
__device__ __forceinline__ void tr_body(float (*tile)[33],
                                        const float* __restrict__ in, u16* __restrict__ out,
                                        int R, int C, int r0, int c0, int t)
{
    const int lr = t >> 3, lc = (t & 7) * 4;
    float4 v = *reinterpret_cast<const float4*>(in + (size_t)(r0 + lr) * C + c0 + lc);
    tile[lr][lc + 0] = v.x; tile[lr][lc + 1] = v.y;
    tile[lr][lc + 2] = v.z; tile[lr][lc + 3] = v.w;
    __syncthreads();
    const int oc = t >> 3, orr = (t & 7) * 4;
    ushort4 o = make_ushort4(f2bf(tile[orr + 0][oc]), f2bf(tile[orr + 1][oc]),
                             f2bf(tile[orr + 2][oc]), f2bf(tile[orr + 3][oc]));
    *reinterpret_cast<ushort4*>(out + (size_t)(c0 + oc) * R + r0 + orr) = o;
}

// ---------- merged prep: x->bf16 + all weight transposes, one launch ----------
__global__ __launch_bounds__(256)
void prep_all(const float* __restrict__ x,    u16* __restrict__ xb,
              const float* __restrict__ Win,  u16* __restrict__ WinT,
              const float* __restrict__ Wout, u16* __restrict__ WoutT,
              const float* __restrict__ Wdt,  const float* __restrict__ WB,
              const float* __restrict__ WC,   u16* __restrict__ WdtbcT,
              const float* __restrict__ Wsi,  u16* __restrict__ WsiT)
{
    const int t = threadIdx.x;
    int b = blockIdx.x;
    if (b < 8192) {                       // convert x (2M ushort4)
        long i = (long)b * 256 + t;
        float4 v = reinterpret_cast<const float4*>(x)[i];
        ushort4 o = make_ushort4(f2bf(v.x), f2bf(v.y), f2bf(v.z), f2bf(v.w));
        reinterpret_cast<ushort4*>(xb)[i] = o;
        return;
    }
    __shared__ float tile[32][33];
    b -= 8192;
    if (b < 4096) {                       // W_in [1024][4096] -> [4096][1024]
        tr_body(tile, Win, WinT, 1024, 4096, (b / 128) * 32, (b % 128) * 32, t);
        return;
    }
    b -= 4096;
    if (b < 2048) {                       // W_out [2048][1024] -> [1024][2048]
        tr_body(tile, Wout, WoutT, 2048, 1024, (b % 64) * 32, (b / 64) * 32, t);
        return;
    }
    b -= 2048;
    if (b < 384) {                        // W_dt/W_B/W_C [2048][64] -> [64][2048]
        const int z = b / 128, rem = b % 128;
        const float* in = (z == 0) ? Wdt : (z == 1) ? WB : WC;
        u16* outp = WdtbcT + (size_t)z * 64 * 2048;
        tr_body(tile, in, outp, 2048, 64, (rem / 2) * 32, (rem % 2) * 32, t);
        return;
    }
    b -= 384;                             // W_si [64][2048] -> [2048][64]
    tr_body(tile, Wsi, WsiT, 64, 2048, (b % 2) * 32, (b / 2) * 32, t);
}

// ---------- 2-barrier MFMA GEMM: C[M][N] = A[M][K] @ Bt[N][K]^T ----------
// Templated BK (64 or 128), linear-LDS global_load_lds w16, both-sides XOR
// swizzle (16B-slot s of row r holds global slot s^(r&7)).
// EPI 0: fp32 out ldc=N     (gemm_out)
// EPI 1: bf16 out ldc=N     (gemm_in)
// EPI 2: fp32 TRANSPOSED out [N][8192]; bias b0|b1|b2 per 64-col; sigmoid col<64
// EPI 3: mix: bf16 out = (acc + b_si + D*xact) * sigmoid(gate)
template <int BM, int BN, int BK, int WM, int WN, int MINW, int EPI>
__global__ __launch_bounds__(WM * WN * 64, MINW)
void gemm_mfma(const u16* __restrict__ A, const u16* __restrict__ Bt,
               const float* __restrict__ b0, const float* __restrict__ b1,
               const float* __restrict__ b2,
               const u16* __restrict__ aux0, const u16* __restrict__ aux1,
               void* __restrict__ o0, int N, int K, int nbx)
{
    constexpr int WAVES = WM * WN;
    constexpr int FM = BM / WM / 16, FN = BN / WN / 16;
    constexpr int LPR = BK / 8;            // lanes per LDS row (staging)
    constexpr int RPC = 64 / LPR;          // rows per 1KB staging chunk
    constexpr int CA  = BM * BK / 512 / WAVES;   // A chunks per wave
    constexpr int CB  = BN * BK / 512 / WAVES;   // B chunks per wave
    constexpr int NKK = BK / 32;           // MFMA K-subtiles per step
    __shared__ __align__(16) u16 As[BM][BK];
    __shared__ __align__(16) u16 Bs[BN][BK];

    const int tid  = threadIdx.x;
    const int lane = tid & 63;
    const int wid  = tid >> 6;
    const int wr   = (wid / WN) * (BM / WM);
    const int wc   = (wid % WN) * (BN / WN);
    const int swz  = xcd_swizzle(blockIdx.x, gridDim.x);
    const int row0 = (swz / nbx) * BM;
    const int col0 = (swz % nbx) * BN;

    const int srow = lane / LPR;           // row within chunk
    const int slot = lane % LPR;           // 16B slot within row
    const int fr   = lane & 15;
    const int fq   = lane >> 4;

    f32x4 acc[FM][FN];
#pragma unroll
    for (int m = 0; m < FM; ++m)
#pragma unroll
        for (int n = 0; n < FN; ++n) acc[m][n] = (f32x4){0.f, 0.f, 0.f, 0.f};

    for (int k0 = 0; k0 < K; k0 += BK) {
#pragma unroll
        for (int i = 0; i < CA; ++i) {
            const int c   = wid * CA + i;
            const int row = c * RPC + srow;
            const int sc  = (slot ^ (row & 7)) * 8;   // pre-swizzled global col
            gll16(A + (size_t)(row0 + row) * K + k0 + sc,
                  &As[0][0] + c * 512 + lane * 8);
        }
#pragma unroll
        for (int i = 0; i < CB; ++i) {
            const int c   = wid * CB + i;
            const int row = c * RPC + srow;
            const int sc  = (slot ^ (row & 7)) * 8;
            gll16(Bt + (size_t)(col0 + row) * K + k0 + sc,
                  &Bs[0][0] + c * 512 + lane * 8);
        }
        __syncthreads();
#pragma unroll
        for (int kk = 0; kk < NKK; ++kk) {
            bf16x8 af[FM], bg[FN];
#pragma unroll
            for (int m = 0; m < FM; ++m) {
                const int rr = wr + m * 16 + fr;
                af[m] = *reinterpret_cast<const bf16x8*>(
                    &As[rr][((kk * 4 + fq) ^ (rr & 7)) * 8]);
            }
#pragma unroll
            for (int n = 0; n < FN; ++n) {
                const int rr = wc + n * 16 + fr;
                bg[n] = *reinterpret_cast<const bf16x8*>(
                    &Bs[rr][((kk * 4 + fq) ^ (rr & 7)) * 8]);
            }
#pragma unroll
            for (int m = 0; m < FM; ++m)
#pragma unroll
                for (int n = 0; n < FN; ++n)
                    acc[m][n] = __builtin_amdgcn_mfma_f32_16x16x32_bf16(af[m], bg[n], acc[m][n], 0, 0, 0);
        }
        __syncthreads();
    }

#pragma unroll
    for (int m = 0; m < FM; ++m) {
#pragma unroll
        for (int n = 0; n < FN; ++n) {
            const int gc  = col0 + wc + n * 16 + fr;
            const int gr0 = row0 + wr + m * 16 + fq * 4;
            if constexpr (EPI == 2) {
                float4 vv;
                float* vp = (float*)&vv;
#pragma unroll
                for (int j = 0; j < 4; ++j) {
                    float bb = (gc < 64) ? b0[gc] : (gc < 128) ? b1[gc - 64] : b2[gc - 128];
                    float v = acc[m][n][j] + bb;
                    if (gc < 64) v = sigmoid_f(v);
                    vp[j] = v;
                }
                *reinterpret_cast<float4*>(&((float*)o0)[(size_t)gc * 8192 + gr0]) = vv;
            } else {
#pragma unroll
                for (int j = 0; j < 4; ++j) {
                    const int gr = gr0 + j;
                    float v = acc[m][n][j];
                    if constexpr (EPI == 0) {
                        ((float*)o0)[(size_t)gr * N + gc] = v + b0[gc];
                    } else if constexpr (EPI == 1) {
                        ((u16*)o0)[(size_t)gr * N + gc] = f2bf(v + b0[gc]);
                    } else {  // EPI 3: mix
                        const size_t p = (size_t)gr * 2048 + gc;
                        float g  = bf2f(aux0[(size_t)gr * 4096 + gc]);   // gate
                        float xa = bf2f(aux1[p]);                        // xact
                        v = v + b0[gc] + b1[gc] * xa;
                        ((u16*)o0)[p] = f2bf(v * sigmoid_f(g));
                    }
                }
            }
        }
    }
    (void)b1; (void)b2; (void)aux0; (void)aux1;
}

// ---------- depthwise causal conv (K=3) + bias + SiLU, bf16 in/out ----------
__global__ __launch_bounds__(256)
void conv_silu(const u16* __restrict__ xz, const float* __restrict__ cw,
               const float* __restrict__ cb, u16* __restrict__ xact)
{
    const size_t g  = ((size_t)blockIdx.x * 256 + threadIdx.x) * 8;
    const int    c0 = (int)(g & 2047);
    const size_t r  = g >> 11;
    const int    s  = (int)(r & (kSeq - 1));
    const u16* p = xz + r * 4096 + c0;
    u16 X0[8], X1[8] = {}, X2[8] = {};
    *reinterpret_cast<uint4*>(X0) = *reinterpret_cast<const uint4*>(p);
    if (s >= 1) *reinterpret_cast<uint4*>(X1) = *reinterpret_cast<const uint4*>(p - 4096);
    if (s >= 2) *reinterpret_cast<uint4*>(X2) = *reinterpret_cast<const uint4*>(p - 8192);
    u16 O[8];
#pragma unroll
    for (int j = 0; j < 8; ++j) {
        const int c = c0 + j;
        float v = bf2f(X2[j]) * cw[c * 3 + 0] + bf2f(X1[j]) * cw[c * 3 + 1]
                + bf2f(X0[j]) * cw[c * 3 + 2] + cb[c];
        O[j] = f2bf(v * sigmoid_f(v));
    }
    *reinterpret_cast<uint4*>(xact + r * 2048 + c0) = *reinterpret_cast<uint4*>(O);
}

// ---------- selective scan over transposed dtbcT [192][8192] ----------
__global__ __launch_bounds__(256)
void scan_kernel(const float* __restrict__ dtbcT, float* __restrict__ y)
{
    const int b = blockIdx.x >> 6;
    const int d = blockIdx.x & 63;
    const int t = threadIdx.x;
    const size_t col = (size_t)b * kSeq + t * 16;
    const float* dtp = dtbcT + (size_t)d         * 8192 + col;
    const float* Bp  = dtbcT + (size_t)(64 + d)  * 8192 + col;
    const float* Cp  = dtbcT + (size_t)(128 + d) * 8192 + col;

    float av[16], bv[16];
    float Acc = 1.f, Bcc = 0.f;
#pragma unroll
    for (int q = 0; q < 4; ++q) {
        float4 dv = *reinterpret_cast<const float4*>(dtp + q * 4);
        float4 Bv = *reinterpret_cast<const float4*>(Bp + q * 4);
        const float* dvp = (const float*)&dv;
        const float* bvp = (const float*)&Bv;
#pragma unroll
        for (int j = 0; j < 4; ++j) {
            const int i = q * 4 + j;
            float a  = 1.f - dvp[j];
            float bb = dvp[j] * bvp[j];
            av[i] = a; bv[i] = bb;
            Acc = a * Acc;
            Bcc = a * Bcc + bb;
        }
    }

    __shared__ float sA[256], sB[256];
    sA[t] = Acc; sB[t] = Bcc;
    __syncthreads();
    for (int off = 1; off < 256; off <<= 1) {
        float cA = sA[t], cB = sB[t];
        float pA = 1.f, pB = 0.f;
        if (t >= off) { pA = sA[t - off]; pB = sB[t - off]; }
        __syncthreads();
        if (t >= off) { sA[t] = cA * pA; sB[t] = cA * pB + cB; }
        __syncthreads();
    }

    float s = (t == 0) ? 0.f : sB[t - 1];
#pragma unroll
    for (int q = 0; q < 4; ++q) {
        float4 Cv = *reinterpret_cast<const float4*>(Cp + q * 4);
        const float* cvp = (const float*)&Cv;
#pragma unroll
        for (int j = 0; j < 4; ++j) {
            const int i = q * 4 + j;
            s = av[i] * s + bv[i];
            y[(col + i) * 64 + d] = cvp[j] * s;
        }
    }
}

// ---------- LayerNorm over 64 states -> bf16 ----------
__global__ __launch_bounds__(256)
void ln_kernel(const float* __restrict__ y, u16* __restrict__ ynb)
{
    const int w = threadIdx.x >> 6;
    const int l = threadIdx.x & 63;
    const size_t r = (size_t)blockIdx.x * 4 + w;
    float v  = y[r * 64 + l];
    float s  = v, s2 = v * v;
#pragma unroll
    for (int m = 1; m < 64; m <<= 1) {
        s  += __shfl_xor(s, m, 64);
        s2 += __shfl_xor(s2, m, 64);
    }
    float mu  = s * (1.f / 64.f);
    float var = s2 * (1.f / 64.f) - mu * mu;
    ynb[r * 64 + l] = f2bf((v - mu) * rsqrtf(var + 1e-5f));
}

}  // namespace

extern "C" void kernel_launch(void* const* d_in, const int* in_sizes, int n_in,
                              void* d_out, int out_size, void* d_ws, size_t ws_size,
                              hipStream_t stream)
{
    (void)in_sizes; (void)n_in; (void)out_size; (void)ws_size;
    const float* x     = (const float*)d_in[0];
    const float* W_in  = (const float*)d_in[1];
    const float* b_in  = (const float*)d_in[2];
    const float* cw    = (const float*)d_in[3];
    const float* cb    = (const float*)d_in[4];
    const float* W_dt  = (const float*)d_in[5];
    const float* b_dt  = (const float*)d_in[6];
    const float* W_B   = (const float*)d_in[7];
    const float* b_B   = (const float*)d_in[8];
    const float* W_C   = (const float*)d_in[9];
    const float* b_C   = (const float*)d_in[10];
    const float* W_si  = (const float*)d_in[11];
    const float* b_si  = (const float*)d_in[12];
    const float* Dv    = (const float*)d_in[13];
    const float* W_out = (const float*)d_in[14];
    const float* b_out = (const float*)d_in[15];
    float* out = (float*)d_out;

    char* ws = (char*)d_ws;
    u16*   xzb    = (u16*)  (ws);
    u16*   xb     = (u16*)  (ws + 67108864);
    u16*   xact   = (u16*)  (ws + 83886080);
    u16*   hb     = (u16*)  (ws + 117440512);
    float* dtbcT  = (float*)(ws + 150994944);
    float* ybuf   = (float*)(ws + 157286400);
    u16*   ynb    = (u16*)  (ws + 159383552);
    u16*   WinT   = (u16*)  (ws + 160432128);
    u16*   WoutT  = (u16*)  (ws + 168820736);
    u16*   WdtbcT = (u16*)  (ws + 173015040);
    u16*   WsiT   = (u16*)  (ws + 173801472);

    dim3 blk(256);
    dim3 blk512(512);

    // merged prep: x->bf16 + all weight transposes (one launch)
    prep_all<<<dim3(8192 + 4096 + 2048 + 384 + 128), blk, 0, stream>>>(
        x, xb, W_in, WinT, W_out, WoutT, W_dt, W_B, W_C, WdtbcT, W_si, WsiT);

    // xzb = bf16(x @ W_in + b_in)   [8192][4096]  (8-wave, BK=64 — measured best)
    gemm_mfma<128, 128, 64, 2, 4, 4, 1><<<dim3(32 * 64), blk512, 0, stream>>>(
        xb, WinT, b_in, nullptr, nullptr, nullptr, nullptr, xzb, 4096, 1024, 32);
    // xact = silu(causal_conv(xzb[:, :2048]))
    conv_silu<<<dim3(8192L * 2048 / (8 * 256)), blk, 0, stream>>>(xzb, cw, cb, xact);
    // dtbcT[192][8192] = [sigmoid(xact@W_dt+b) | xact@W_B+b | xact@W_C+b]^T  (BK=64)
    gemm_mfma<64, 64, 64, 2, 4, 4, 2><<<dim3(3 * 128), blk512, 0, stream>>>(
        xact, WdtbcT, b_dt, b_B, b_C, nullptr, nullptr, dtbcT, 192, 2048, 3);
    // y = selective_scan(dt, B, C)   [8192][64]
    scan_kernel<<<dim3(128), blk, 0, stream>>>(dtbcT, ybuf);
    // ynb = bf16(layernorm(y))
    ln_kernel<<<dim3(8192 / 4), blk, 0, stream>>>(ybuf, ynb);
    // hb = (ynb@W_si + b_si + D*xact) * sigmoid(gate)   (BK=64: K is 64)
    gemm_mfma<128, 128, 64, 2, 4, 4, 3><<<dim3(16 * 64), blk512, 0, stream>>>(
        ynb, WsiT, b_si, Dv, nullptr, xzb + 2048, xact, hb, 2048, 64, 16);
    // out = hb @ W_out + b_out   (8-wave, BK=128 — kept from R13)
    gemm_mfma<128, 128, 128, 2, 4, 4, 0><<<dim3(8 * 64), blk512, 0, stream>>>(
        hb, WoutT, b_out, nullptr, nullptr, nullptr, nullptr, out, 1024, 2048, 8);
}

// Round 15
// 228.180 us; speedup vs baseline: 1.0172x; 1.0172x over previous
//
#include <hip/hip_runtime.h>
#include <hip/hip_bf16.h>
#include <math.h>

// SelectiveStateSpaceMixer — round 15: R14 config + coalesced scan output
// (yT[64][8192] transposed, float4 stores) + tiled LDS-transpose LayerNorm.
// ws layout (bytes):
//   xzb    bf16[8192][4096]  67108864 @ 0
//   xb     bf16[8192][1024]  16777216 @ 67108864
//   xact   bf16[8192][2048]  33554432 @ 83886080
//   hb     bf16[8192][2048]  33554432 @ 117440512
//   dtbcT  f32 [192][8192]    6291456 @ 150994944
//   yT     f32 [64][8192]     2097152 @ 157286400
//   ynb    bf16[8192][64]     1048576 @ 159383552
//   WinT   bf16[4096][1024]   8388608 @ 160432128
//   WoutT  bf16[1024][2048]   4194304 @ 168820736
//   WdtbcT bf16[192][2048]     786432 @ 173015040
//   WsiT   bf16[2048][64]      262144 @ 173801472   end 174063616

namespace {

typedef __bf16 bf16x8 __attribute__((ext_vector_type(8)));
typedef float  f32x4  __attribute__((ext_vector_type(4)));
typedef unsigned short u16;

constexpr int kSeq = 4096;

__device__ __forceinline__ float sigmoid_f(float x) { return 1.0f / (1.0f + expf(-x)); }
__device__ __forceinline__ u16   f2bf(float f) { __bf16 h = (__bf16)f; return __builtin_bit_cast(u16, h); }
__device__ __forceinline__ float bf2f(u16 u)   { return (float)__builtin_bit_cast(__bf16, u); }

// async global->LDS, 16B per lane (dest = wave-uniform base + lane*16)
__device__ __forceinline__ void gll16(const u16* g, u16* l) {
    __builtin_amdgcn_global_load_lds(
        (const __attribute__((address_space(1))) unsigned int*)g,
        (__attribute__((address_space(3))) unsigned int*)l,
        16, 0, 0);
}

// bijective XCD-aware block swizzle (m204)
__device__ __forceinline__ int xcd_swizzle(int lin, int nwg) {
    const int q = nwg >> 3, r = nwg & 7;
    const int xcd = lin & 7, idx = lin >> 3;
    return (xcd < r ? xcd * (q + 1) : r * (q + 1) + (xcd - r) * q) + idx;
}

// ---------- 32x32 tile transpose body: fp32 [R][C] -> bf16 [C][R] ----------
__device__ __forceinline__ void tr_body(float (*tile)[33],
                                        const float* __restrict__ in, u16* __restrict__ out,
                                        int R, int C, int r0, int c0, int t)
{
    const int lr = t >> 3, lc = (t & 7) * 4;
    float4 v = *reinterpret_cast<const float4*>(in + (size_t)(r0 + lr) * C + c0 + lc);
    tile[lr][lc + 0] = v.x; tile[lr][lc + 1] = v.y;
    tile[lr][lc + 2] = v.z; tile[lr][lc + 3] = v.w;
    __syncthreads();
    const int oc = t >> 3, orr = (t & 7) * 4;
    ushort4 o = make_ushort4(f2bf(tile[orr + 0][oc]), f2bf(tile[orr + 1][oc]),
                             f2bf(tile[orr + 2][oc]), f2bf(tile[orr + 3][oc]));
    *reinterpret_cast<ushort4*>(out + (size_t)(c0 + oc) * R + r0 + orr) = o;
}

// ---------- merged prep: x->bf16 + all weight transposes, one launch ----------
__global__ __launch_bounds__(256)
void prep_all(const float* __restrict__ x,    u16* __restrict__ xb,
              const float* __restrict__ Win,  u16* __restrict__ WinT,
              const float* __restrict__ Wout, u16* __restrict__ WoutT,
              const float* __restrict__ Wdt,  const float* __restrict__ WB,
              const float* __restrict__ WC,   u16* __restrict__ WdtbcT,
              const float* __restrict__ Wsi,  u16* __restrict__ WsiT)
{
    const int t = threadIdx.x;
    int b = blockIdx.x;
    if (b < 8192) {                       // convert x (2M ushort4)
        long i = (long)b * 256 + t;
        float4 v = reinterpret_cast<const float4*>(x)[i];
        ushort4 o = make_ushort4(f2bf(v.x), f2bf(v.y), f2bf(v.z), f2bf(v.w));
        reinterpret_cast<ushort4*>(xb)[i] = o;
        return;
    }
    __shared__ float tile[32][33];
    b -= 8192;
    if (b < 4096) {                       // W_in [1024][4096] -> [4096][1024]
        tr_body(tile, Win, WinT, 1024, 4096, (b / 128) * 32, (b % 128) * 32, t);
        return;
    }
    b -= 4096;
    if (b < 2048) {                       // W_out [2048][1024] -> [1024][2048]
        tr_body(tile, Wout, WoutT, 2048, 1024, (b % 64) * 32, (b / 64) * 32, t);
        return;
    }
    b -= 2048;
    if (b < 384) {                        // W_dt/W_B/W_C [2048][64] -> [64][2048]
        const int z = b / 128, rem = b % 128;
        const float* in = (z == 0) ? Wdt : (z == 1) ? WB : WC;
        u16* outp = WdtbcT + (size_t)z * 64 * 2048;
        tr_body(tile, in, outp, 2048, 64, (rem / 2) * 32, (rem % 2) * 32, t);
        return;
    }
    b -= 384;                             // W_si [64][2048] -> [2048][64]
    tr_body(tile, Wsi, WsiT, 64, 2048, (b % 2) * 32, (b / 2) * 32, t);
}

// ---------- 2-barrier MFMA GEMM: C[M][N] = A[M][K] @ Bt[N][K]^T ----------
// Templated BK (64 or 128), linear-LDS global_load_lds w16, both-sides XOR
// swizzle (16B-slot s of row r holds global slot s^(r&7)).
// EPI 0: fp32 out ldc=N     (gemm_out)
// EPI 1: bf16 out ldc=N     (gemm_in)
// EPI 2: fp32 TRANSPOSED out [N][8192]; bias b0|b1|b2 per 64-col; sigmoid col<64
// EPI 3: mix: bf16 out = (acc + b_si + D*xact) * sigmoid(gate)
template <int BM, int BN, int BK, int WM, int WN, int MINW, int EPI>
__global__ __launch_bounds__(WM * WN * 64, MINW)
void gemm_mfma(const u16* __restrict__ A, const u16* __restrict__ Bt,
               const float* __restrict__ b0, const float* __restrict__ b1,
               const float* __restrict__ b2,
               const u16* __restrict__ aux0, const u16* __restrict__ aux1,
               void* __restrict__ o0, int N, int K, int nbx)
{
    constexpr int WAVES = WM * WN;
    constexpr int FM = BM / WM / 16, FN = BN / WN / 16;
    constexpr int LPR = BK / 8;            // lanes per LDS row (staging)
    constexpr int RPC = 64 / LPR;          // rows per 1KB staging chunk
    constexpr int CA  = BM * BK / 512 / WAVES;   // A chunks per wave
    constexpr int CB  = BN * BK / 512 / WAVES;   // B chunks per wave
    constexpr int NKK = BK / 32;           // MFMA K-subtiles per step
    __shared__ __align__(16) u16 As[BM][BK];
    __shared__ __align__(16) u16 Bs[BN][BK];

    const int tid  = threadIdx.x;
    const int lane = tid & 63;
    const int wid  = tid >> 6;
    const int wr   = (wid / WN) * (BM / WM);
    const int wc   = (wid % WN) * (BN / WN);
    const int swz  = xcd_swizzle(blockIdx.x, gridDim.x);
    const int row0 = (swz / nbx) * BM;
    const int col0 = (swz % nbx) * BN;

    const int srow = lane / LPR;           // row within chunk
    const int slot = lane % LPR;           // 16B slot within row
    const int fr   = lane & 15;
    const int fq   = lane >> 4;

    f32x4 acc[FM][FN];
#pragma unroll
    for (int m = 0; m < FM; ++m)
#pragma unroll
        for (int n = 0; n < FN; ++n) acc[m][n] = (f32x4){0.f, 0.f, 0.f, 0.f};

    for (int k0 = 0; k0 < K; k0 += BK) {
#pragma unroll
        for (int i = 0; i < CA; ++i) {
            const int c   = wid * CA + i;
            const int row = c * RPC + srow;
            const int sc  = (slot ^ (row & 7)) * 8;   // pre-swizzled global col
            gll16(A + (size_t)(row0 + row) * K + k0 + sc,
                  &As[0][0] + c * 512 + lane * 8);
        }
#pragma unroll
        for (int i = 0; i < CB; ++i) {
            const int c   = wid * CB + i;
            const int row = c * RPC + srow;
            const int sc  = (slot ^ (row & 7)) * 8;
            gll16(Bt + (size_t)(col0 + row) * K + k0 + sc,
                  &Bs[0][0] + c * 512 + lane * 8);
        }
        __syncthreads();
#pragma unroll
        for (int kk = 0; kk < NKK; ++kk) {
            bf16x8 af[FM], bg[FN];
#pragma unroll
            for (int m = 0; m < FM; ++m) {
                const int rr = wr + m * 16 + fr;
                af[m] = *reinterpret_cast<const bf16x8*>(
                    &As[rr][((kk * 4 + fq) ^ (rr & 7)) * 8]);
            }
#pragma unroll
            for (int n = 0; n < FN; ++n) {
                const int rr = wc + n * 16 + fr;
                bg[n] = *reinterpret_cast<const bf16x8*>(
                    &Bs[rr][((kk * 4 + fq) ^ (rr & 7)) * 8]);
            }
#pragma unroll
            for (int m = 0; m < FM; ++m)
#pragma unroll
                for (int n = 0; n < FN; ++n)
                    acc[m][n] = __builtin_amdgcn_mfma_f32_16x16x32_bf16(af[m], bg[n], acc[m][n], 0, 0, 0);
        }
        __syncthreads();
    }

#pragma unroll
    for (int m = 0; m < FM; ++m) {
#pragma unroll
        for (int n = 0; n < FN; ++n) {
            const int gc  = col0 + wc + n * 16 + fr;
            const int gr0 = row0 + wr + m * 16 + fq * 4;
            if constexpr (EPI == 2) {
                float4 vv;
                float* vp = (float*)&vv;
#pragma unroll
                for (int j = 0; j < 4; ++j) {
                    float bb = (gc < 64) ? b0[gc] : (gc < 128) ? b1[gc - 64] : b2[gc - 128];
                    float v = acc[m][n][j] + bb;
                    if (gc < 64) v = sigmoid_f(v);
                    vp[j] = v;
                }
                *reinterpret_cast<float4*>(&((float*)o0)[(size_t)gc * 8192 + gr0]) = vv;
            } else {
#pragma unroll
                for (int j = 0; j < 4; ++j) {
                    const int gr = gr0 + j;
                    float v = acc[m][n][j];
                    if constexpr (EPI == 0) {
                        ((float*)o0)[(size_t)gr * N + gc] = v + b0[gc];
                    } else if constexpr (EPI == 1) {
                        ((u16*)o0)[(size_t)gr * N + gc] = f2bf(v + b0[gc]);
                    } else {  // EPI 3: mix
                        const size_t p = (size_t)gr * 2048 + gc;
                        float g  = bf2f(aux0[(size_t)gr * 4096 + gc]);   // gate
                        float xa = bf2f(aux1[p]);                        // xact
                        v = v + b0[gc] + b1[gc] * xa;
                        ((u16*)o0)[p] = f2bf(v * sigmoid_f(g));
                    }
                }
            }
        }
    }
    (void)b1; (void)b2; (void)aux0; (void)aux1;
}

// ---------- depthwise causal conv (K=3) + bias + SiLU, bf16 in/out ----------
__global__ __launch_bounds__(256)
void conv_silu(const u16* __restrict__ xz, const float* __restrict__ cw,
               const float* __restrict__ cb, u16* __restrict__ xact)
{
    const size_t g  = ((size_t)blockIdx.x * 256 + threadIdx.x) * 8;
    const int    c0 = (int)(g & 2047);
    const size_t r  = g >> 11;
    const int    s  = (int)(r & (kSeq - 1));
    const u16* p = xz + r * 4096 + c0;
    u16 X0[8], X1[8] = {}, X2[8] = {};
    *reinterpret_cast<uint4*>(X0) = *reinterpret_cast<const uint4*>(p);
    if (s >= 1) *reinterpret_cast<uint4*>(X1) = *reinterpret_cast<const uint4*>(p - 4096);
    if (s >= 2) *reinterpret_cast<uint4*>(X2) = *reinterpret_cast<const uint4*>(p - 8192);
    u16 O[8];
#pragma unroll
    for (int j = 0; j < 8; ++j) {
        const int c = c0 + j;
        float v = bf2f(X2[j]) * cw[c * 3 + 0] + bf2f(X1[j]) * cw[c * 3 + 1]
                + bf2f(X0[j]) * cw[c * 3 + 2] + cb[c];
        O[j] = f2bf(v * sigmoid_f(v));
    }
    *reinterpret_cast<uint4*>(xact + r * 2048 + c0) = *reinterpret_cast<uint4*>(O);
}

// ---------- selective scan over dtbcT [192][8192] -> yT [64][8192] ----------
// coalesced float4 reads AND writes (yT transposed layout)
__global__ __launch_bounds__(256)
void scan_kernel(const float* __restrict__ dtbcT, float* __restrict__ yT)
{
    const int b = blockIdx.x >> 6;
    const int d = blockIdx.x & 63;
    const int t = threadIdx.x;
    const size_t col = (size_t)b * kSeq + t * 16;
    const float* dtp = dtbcT + (size_t)d         * 8192 + col;
    const float* Bp  = dtbcT + (size_t)(64 + d)  * 8192 + col;
    const float* Cp  = dtbcT + (size_t)(128 + d) * 8192 + col;

    float av[16], bv[16];
    float Acc = 1.f, Bcc = 0.f;
#pragma unroll
    for (int q = 0; q < 4; ++q) {
        float4 dv = *reinterpret_cast<const float4*>(dtp + q * 4);
        float4 Bv = *reinterpret_cast<const float4*>(Bp + q * 4);
        const float* dvp = (const float*)&dv;
        const float* bvp = (const float*)&Bv;
#pragma unroll
        for (int j = 0; j < 4; ++j) {
            const int i = q * 4 + j;
            float a  = 1.f - dvp[j];
            float bb = dvp[j] * bvp[j];
            av[i] = a; bv[i] = bb;
            Acc = a * Acc;
            Bcc = a * Bcc + bb;
        }
    }

    __shared__ float sA[256], sB[256];
    sA[t] = Acc; sB[t] = Bcc;
    __syncthreads();
    for (int off = 1; off < 256; off <<= 1) {
        float cA = sA[t], cB = sB[t];
        float pA = 1.f, pB = 0.f;
        if (t >= off) { pA = sA[t - off]; pB = sB[t - off]; }
        __syncthreads();
        if (t >= off) { sA[t] = cA * pA; sB[t] = cA * pB + cB; }
        __syncthreads();
    }

    float s = (t == 0) ? 0.f : sB[t - 1];
#pragma unroll
    for (int q = 0; q < 4; ++q) {
        float4 Cv = *reinterpret_cast<const float4*>(Cp + q * 4);
        const float* cvp = (const float*)&Cv;
        float4 ov;
        float* op = (float*)&ov;
#pragma unroll
        for (int j = 0; j < 4; ++j) {
            const int i = q * 4 + j;
            s = av[i] * s + bv[i];
            op[j] = cvp[j] * s;
        }
        *reinterpret_cast<float4*>(&yT[(size_t)d * 8192 + col + q * 4]) = ov;
    }
}

// ---------- LayerNorm over 64 states: yT [64][8192] -> ynb [8192][64] bf16 ----
// tiled: 64 blocks x 128 rows; LDS-transposed tile, conflict-free reads.
__global__ __launch_bounds__(256)
void ln_kernel(const float* __restrict__ yT, u16* __restrict__ ynb)
{
    __shared__ float tile[64][132];
    __shared__ float ps[2][128], ps2[2][128];
    const int t  = threadIdx.x;
    const int r0 = blockIdx.x * 128;
    const int d  = t >> 2;
    const int cb = (t & 3) * 32;
#pragma unroll
    for (int j = 0; j < 8; ++j) {
        float4 v = *reinterpret_cast<const float4*>(&yT[(size_t)d * 8192 + r0 + cb + j * 4]);
        *reinterpret_cast<float4*>(&tile[d][cb + j * 4]) = v;
    }
    __syncthreads();
    const int r = t & 127, h = t >> 7;
    float s = 0.f, s2 = 0.f;
#pragma unroll
    for (int d2 = 0; d2 < 32; ++d2) {
        float v = tile[h * 32 + d2][r];
        s += v; s2 += v * v;
    }
    ps[h][r] = s; ps2[h][r] = s2;
    __syncthreads();
    const float S   = ps[0][r] + ps[1][r];
    const float S2  = ps2[0][r] + ps2[1][r];
    const float mu  = S * (1.f / 64.f);
    const float inv = rsqrtf(S2 * (1.f / 64.f) - mu * mu + 1e-5f);
    u16 o[32];
#pragma unroll
    for (int d2 = 0; d2 < 32; ++d2)
        o[d2] = f2bf((tile[h * 32 + d2][r] - mu) * inv);
#pragma unroll
    for (int q = 0; q < 4; ++q)
        *reinterpret_cast<uint4*>(&ynb[(size_t)(r0 + r) * 64 + h * 32 + q * 8]) =
            *reinterpret_cast<const uint4*>(&o[q * 8]);
}

}  // namespace

extern "C" void kernel_launch(void* const* d_in, const int* in_sizes, int n_in,
                              void* d_out, int out_size, void* d_ws, size_t ws_size,
                              hipStream_t stream)
{
    (void)in_sizes; (void)n_in; (void)out_size; (void)ws_size;
    const float* x     = (const float*)d_in[0];
    const float* W_in  = (const float*)d_in[1];
    const float* b_in  = (const float*)d_in[2];
    const float* cw    = (const float*)d_in[3];
    const float* cb    = (const float*)d_in[4];
    const float* W_dt  = (const float*)d_in[5];
    const float* b_dt  = (const float*)d_in[6];
    const float* W_B   = (const float*)d_in[7];
    const float* b_B   = (const float*)d_in[8];
    const float* W_C   = (const float*)d_in[9];
    const float* b_C   = (const float*)d_in[10];
    const float* W_si  = (const float*)d_in[11];
    const float* b_si  = (const float*)d_in[12];
    const float* Dv    = (const float*)d_in[13];
    const float* W_out = (const float*)d_in[14];
    const float* b_out = (const float*)d_in[15];
    float* out = (float*)d_out;

    char* ws = (char*)d_ws;
    u16*   xzb    = (u16*)  (ws);
    u16*   xb     = (u16*)  (ws + 67108864);
    u16*   xact   = (u16*)  (ws + 83886080);
    u16*   hb     = (u16*)  (ws + 117440512);
    float* dtbcT  = (float*)(ws + 150994944);
    float* yT     = (float*)(ws + 157286400);
    u16*   ynb    = (u16*)  (ws + 159383552);
    u16*   WinT   = (u16*)  (ws + 160432128);
    u16*   WoutT  = (u16*)  (ws + 168820736);
    u16*   WdtbcT = (u16*)  (ws + 173015040);
    u16*   WsiT   = (u16*)  (ws + 173801472);

    dim3 blk(256);
    dim3 blk512(512);

    // merged prep: x->bf16 + all weight transposes (one launch)
    prep_all<<<dim3(8192 + 4096 + 2048 + 384 + 128), blk, 0, stream>>>(
        x, xb, W_in, WinT, W_out, WoutT, W_dt, W_B, W_C, WdtbcT, W_si, WsiT);

    // xzb = bf16(x @ W_in + b_in)   [8192][4096]  (8-wave, BK=64 — measured best)
    gemm_mfma<128, 128, 64, 2, 4, 4, 1><<<dim3(32 * 64), blk512, 0, stream>>>(
        xb, WinT, b_in, nullptr, nullptr, nullptr, nullptr, xzb, 4096, 1024, 32);
    // xact = silu(causal_conv(xzb[:, :2048]))
    conv_silu<<<dim3(8192L * 2048 / (8 * 256)), blk, 0, stream>>>(xzb, cw, cb, xact);
    // dtbcT[192][8192] = [sigmoid(xact@W_dt+b) | xact@W_B+b | xact@W_C+b]^T  (BK=64)
    gemm_mfma<64, 64, 64, 2, 4, 4, 2><<<dim3(3 * 128), blk512, 0, stream>>>(
        xact, WdtbcT, b_dt, b_B, b_C, nullptr, nullptr, dtbcT, 192, 2048, 3);
    // yT[64][8192] = selective_scan(dt, B, C)   (coalesced transposed output)
    scan_kernel<<<dim3(128), blk, 0, stream>>>(dtbcT, yT);
    // ynb = bf16(layernorm over channels)   (tiled LDS-transpose)
    ln_kernel<<<dim3(64), blk, 0, stream>>>(yT, ynb);
    // hb = (ynb@W_si + b_si + D*xact) * sigmoid(gate)   (BK=64: K is 64)
    gemm_mfma<128, 128, 64, 2, 4, 4, 3><<<dim3(16 * 64), blk512, 0, stream>>>(
        ynb, WsiT, b_si, Dv, nullptr, xzb + 2048, xact, hb, 2048, 64, 16);
    // out = hb @ W_out + b_out   (8-wave, BK=128)
    gemm_mfma<128, 128, 128, 2, 4, 4, 0><<<dim3(8 * 64), blk512, 0, stream>>>(
        hb, WoutT, b_out, nullptr, nullptr, nullptr, nullptr, out, 1024, 2048, 8);
}

// Round 16
// 221.032 us; speedup vs baseline: 1.0501x; 1.0323x over previous
//
#include <hip/hip_runtime.h>
#include <hip/hip_bf16.h>
#include <math.h>

// SelectiveStateSpaceMixer — round 16: R15 + 4-row-batched conv (halves read
// traffic) + dtbc BK=128 (halves barrier count). All else frozen at R15.
// ws layout (bytes):
//   xzb    bf16[8192][4096]  67108864 @ 0
//   xb     bf16[8192][1024]  16777216 @ 67108864
//   xact   bf16[8192][2048]  33554432 @ 83886080
//   hb     bf16[8192][2048]  33554432 @ 117440512
//   dtbcT  f32 [192][8192]    6291456 @ 150994944
//   yT     f32 [64][8192]     2097152 @ 157286400
//   ynb    bf16[8192][64]     1048576 @ 159383552
//   WinT   bf16[4096][1024]   8388608 @ 160432128
//   WoutT  bf16[1024][2048]   4194304 @ 168820736
//   WdtbcT bf16[192][2048]     786432 @ 173015040
//   WsiT   bf16[2048][64]      262144 @ 173801472   end 174063616

namespace {

typedef __bf16 bf16x8 __attribute__((ext_vector_type(8)));
typedef float  f32x4  __attribute__((ext_vector_type(4)));
typedef unsigned short u16;

constexpr int kSeq = 4096;

__device__ __forceinline__ float sigmoid_f(float x) { return 1.0f / (1.0f + expf(-x)); }
__device__ __forceinline__ u16   f2bf(float f) { __bf16 h = (__bf16)f; return __builtin_bit_cast(u16, h); }
__device__ __forceinline__ float bf2f(u16 u)   { return (float)__builtin_bit_cast(__bf16, u); }

// async global->LDS, 16B per lane (dest = wave-uniform base + lane*16)
__device__ __forceinline__ void gll16(const u16* g, u16* l) {
    __builtin_amdgcn_global_load_lds(
        (const __attribute__((address_space(1))) unsigned int*)g,
        (__attribute__((address_space(3))) unsigned int*)l,
        16, 0, 0);
}

// bijective XCD-aware block swizzle (m204)
__device__ __forceinline__ int xcd_swizzle(int lin, int nwg) {
    const int q = nwg >> 3, r = nwg & 7;
    const int xcd = lin & 7, idx = lin >> 3;
    return (xcd < r ? xcd * (q + 1) : r * (q + 1) + (xcd - r) * q) + idx;
}

// ---------- 32x32 tile transpose body: fp32 [R][C] -> bf16 [C][R] ----------
__device__ __forceinline__ void tr_body(float (*tile)[33],
                                        const float* __restrict__ in, u16* __restrict__ out,
                                        int R, int C, int r0, int c0, int t)
{
    const int lr = t >> 3, lc = (t & 7) * 4;
    float4 v = *reinterpret_cast<const float4*>(in + (size_t)(r0 + lr) * C + c0 + lc);
    tile[lr][lc + 0] = v.x; tile[lr][lc + 1] = v.y;
    tile[lr][lc + 2] = v.z; tile[lr][lc + 3] = v.w;
    __syncthreads();
    const int oc = t >> 3, orr = (t & 7) * 4;
    ushort4 o = make_ushort4(f2bf(tile[orr + 0][oc]), f2bf(tile[orr + 1][oc]),
                             f2bf(tile[orr + 2][oc]), f2bf(tile[orr + 3][oc]));
    *reinterpret_cast<ushort4*>(out + (size_t)(c0 + oc) * R + r0 + orr) = o;
}

// ---------- merged prep: x->bf16 + all weight transposes, one launch ----------
__global__ __launch_bounds__(256)
void prep_all(const float* __restrict__ x,    u16* __restrict__ xb,
              const float* __restrict__ Win,  u16* __restrict__ WinT,
              const float* __restrict__ Wout, u16* __restrict__ WoutT,
              const float* __restrict__ Wdt,  const float* __restrict__ WB,
              const float* __restrict__ WC,   u16* __restrict__ WdtbcT,
              const float* __restrict__ Wsi,  u16* __restrict__ WsiT)
{
    const int t = threadIdx.x;
    int b = blockIdx.x;
    if (b < 8192) {                       // convert x (2M ushort4)
        long i = (long)b * 256 + t;
        float4 v = reinterpret_cast<const float4*>(x)[i];
        ushort4 o = make_ushort4(f2bf(v.x), f2bf(v.y), f2bf(v.z), f2bf(v.w));
        reinterpret_cast<ushort4*>(xb)[i] = o;
        return;
    }
    __shared__ float tile[32][33];
    b -= 8192;
    if (b < 4096) {                       // W_in [1024][4096] -> [4096][1024]
        tr_body(tile, Win, WinT, 1024, 4096, (b / 128) * 32, (b % 128) * 32, t);
        return;
    }
    b -= 4096;
    if (b < 2048) {                       // W_out [2048][1024] -> [1024][2048]
        tr_body(tile, Wout, WoutT, 2048, 1024, (b % 64) * 32, (b / 64) * 32, t);
        return;
    }
    b -= 2048;
    if (b < 384) {                        // W_dt/W_B/W_C [2048][64] -> [64][2048]
        const int z = b / 128, rem = b % 128;
        const float* in = (z == 0) ? Wdt : (z == 1) ? WB : WC;
        u16* outp = WdtbcT + (size_t)z * 64 * 2048;
        tr_body(tile, in, outp, 2048, 64, (rem / 2) * 32, (rem % 2) * 32, t);
        return;
    }
    b -= 384;                             // W_si [64][2048] -> [2048][64]
    tr_body(tile, Wsi, WsiT, 64, 2048, (b % 2) * 32, (b / 2) * 32, t);
}

// ---------- 2-barrier MFMA GEMM: C[M][N] = A[M][K] @ Bt[N][K]^T ----------
// Templated BK (64 or 128), linear-LDS global_load_lds w16, both-sides XOR
// swizzle (16B-slot s of row r holds global slot s^(r&7)).
// EPI 0: fp32 out ldc=N     (gemm_out)
// EPI 1: bf16 out ldc=N     (gemm_in)
// EPI 2: fp32 TRANSPOSED out [N][8192]; bias b0|b1|b2 per 64-col; sigmoid col<64
// EPI 3: mix: bf16 out = (acc + b_si + D*xact) * sigmoid(gate)
template <int BM, int BN, int BK, int WM, int WN, int MINW, int EPI>
__global__ __launch_bounds__(WM * WN * 64, MINW)
void gemm_mfma(const u16* __restrict__ A, const u16* __restrict__ Bt,
               const float* __restrict__ b0, const float* __restrict__ b1,
               const float* __restrict__ b2,
               const u16* __restrict__ aux0, const u16* __restrict__ aux1,
               void* __restrict__ o0, int N, int K, int nbx)
{
    constexpr int WAVES = WM * WN;
    constexpr int FM = BM / WM / 16, FN = BN / WN / 16;
    constexpr int LPR = BK / 8;            // lanes per LDS row (staging)
    constexpr int RPC = 64 / LPR;          // rows per 1KB staging chunk
    constexpr int CA  = BM * BK / 512 / WAVES;   // A chunks per wave
    constexpr int CB  = BN * BK / 512 / WAVES;   // B chunks per wave
    constexpr int NKK = BK / 32;           // MFMA K-subtiles per step
    __shared__ __align__(16) u16 As[BM][BK];
    __shared__ __align__(16) u16 Bs[BN][BK];

    const int tid  = threadIdx.x;
    const int lane = tid & 63;
    const int wid  = tid >> 6;
    const int wr   = (wid / WN) * (BM / WM);
    const int wc   = (wid % WN) * (BN / WN);
    const int swz  = xcd_swizzle(blockIdx.x, gridDim.x);
    const int row0 = (swz / nbx) * BM;
    const int col0 = (swz % nbx) * BN;

    const int srow = lane / LPR;           // row within chunk
    const int slot = lane % LPR;           // 16B slot within row
    const int fr   = lane & 15;
    const int fq   = lane >> 4;

    f32x4 acc[FM][FN];
#pragma unroll
    for (int m = 0; m < FM; ++m)
#pragma unroll
        for (int n = 0; n < FN; ++n) acc[m][n] = (f32x4){0.f, 0.f, 0.f, 0.f};

    for (int k0 = 0; k0 < K; k0 += BK) {
#pragma unroll
        for (int i = 0; i < CA; ++i) {
            const int c   = wid * CA + i;
            const int row = c * RPC + srow;
            const int sc  = (slot ^ (row & 7)) * 8;   // pre-swizzled global col
            gll16(A + (size_t)(row0 + row) * K + k0 + sc,
                  &As[0][0] + c * 512 + lane * 8);
        }
#pragma unroll
        for (int i = 0; i < CB; ++i) {
            const int c   = wid * CB + i;
            const int row = c * RPC + srow;
            const int sc  = (slot ^ (row & 7)) * 8;
            gll16(Bt + (size_t)(col0 + row) * K + k0 + sc,
                  &Bs[0][0] + c * 512 + lane * 8);
        }
        __syncthreads();
#pragma unroll
        for (int kk = 0; kk < NKK; ++kk) {
            bf16x8 af[FM], bg[FN];
#pragma unroll
            for (int m = 0; m < FM; ++m) {
                const int rr = wr + m * 16 + fr;
                af[m] = *reinterpret_cast<const bf16x8*>(
                    &As[rr][((kk * 4 + fq) ^ (rr & 7)) * 8]);
            }
#pragma unroll
            for (int n = 0; n < FN; ++n) {
                const int rr = wc + n * 16 + fr;
                bg[n] = *reinterpret_cast<const bf16x8*>(
                    &Bs[rr][((kk * 4 + fq) ^ (rr & 7)) * 8]);
            }
#pragma unroll
            for (int m = 0; m < FM; ++m)
#pragma unroll
                for (int n = 0; n < FN; ++n)
                    acc[m][n] = __builtin_amdgcn_mfma_f32_16x16x32_bf16(af[m], bg[n], acc[m][n], 0, 0, 0);
        }
        __syncthreads();
    }

#pragma unroll
    for (int m = 0; m < FM; ++m) {
#pragma unroll
        for (int n = 0; n < FN; ++n) {
            const int gc  = col0 + wc + n * 16 + fr;
            const int gr0 = row0 + wr + m * 16 + fq * 4;
            if constexpr (EPI == 2) {
                float4 vv;
                float* vp = (float*)&vv;
#pragma unroll
                for (int j = 0; j < 4; ++j) {
                    float bb = (gc < 64) ? b0[gc] : (gc < 128) ? b1[gc - 64] : b2[gc - 128];
                    float v = acc[m][n][j] + bb;
                    if (gc < 64) v = sigmoid_f(v);
                    vp[j] = v;
                }
                *reinterpret_cast<float4*>(&((float*)o0)[(size_t)gc * 8192 + gr0]) = vv;
            } else {
#pragma unroll
                for (int j = 0; j < 4; ++j) {
                    const int gr = gr0 + j;
                    float v = acc[m][n][j];
                    if constexpr (EPI == 0) {
                        ((float*)o0)[(size_t)gr * N + gc] = v + b0[gc];
                    } else if constexpr (EPI == 1) {
                        ((u16*)o0)[(size_t)gr * N + gc] = f2bf(v + b0[gc]);
                    } else {  // EPI 3: mix
                        const size_t p = (size_t)gr * 2048 + gc;
                        float g  = bf2f(aux0[(size_t)gr * 4096 + gc]);   // gate
                        float xa = bf2f(aux1[p]);                        // xact
                        v = v + b0[gc] + b1[gc] * xa;
                        ((u16*)o0)[p] = f2bf(v * sigmoid_f(g));
                    }
                }
            }
        }
    }
    (void)b1; (void)b2; (void)aux0; (void)aux1;
}

// ---------- depthwise causal conv (K=3) + bias + SiLU, 4 rows/thread ----------
// thread t covers cols c0..c0+7 of rows r0..r0+3; loads 6 rows (4 + 2 halo).
__global__ __launch_bounds__(256)
void conv_silu(const u16* __restrict__ xz, const float* __restrict__ cw,
               const float* __restrict__ cb, u16* __restrict__ xact)
{
    const int    c0 = threadIdx.x * 8;                 // 0..2040 (full row width)
    const size_t r0 = (size_t)blockIdx.x * 4;          // 4 consecutive seq rows
    const int    s0 = (int)(r0 & (kSeq - 1));          // multiple of 4
    const u16*   p  = xz + r0 * 4096 + c0;

    u16 X[6][8];                                       // rows s0-2 .. s0+3
#pragma unroll
    for (int k = 0; k < 6; ++k) {
        if (k >= 2 || s0 != 0) {
            *reinterpret_cast<uint4*>(X[k]) =
                *reinterpret_cast<const uint4*>(p + ((long)k - 2) * 4096);
        } else {
            *reinterpret_cast<uint4*>(X[k]) = make_uint4(0, 0, 0, 0);
        }
    }
    float w0[8], w1[8], w2[8], bias[8];
#pragma unroll
    for (int j = 0; j < 8; ++j) {
        const int c = c0 + j;
        w0[j] = cw[c * 3 + 0]; w1[j] = cw[c * 3 + 1];
        w2[j] = cw[c * 3 + 2]; bias[j] = cb[c];
    }
#pragma unroll
    for (int i = 0; i < 4; ++i) {
        u16 O[8];
#pragma unroll
        for (int j = 0; j < 8; ++j) {
            float v = bf2f(X[i][j]) * w0[j] + bf2f(X[i + 1][j]) * w1[j]
                    + bf2f(X[i + 2][j]) * w2[j] + bias[j];
            O[j] = f2bf(v * sigmoid_f(v));
        }
        *reinterpret_cast<uint4*>(xact + (r0 + i) * 2048 + c0) =
            *reinterpret_cast<uint4*>(O);
    }
}

// ---------- selective scan over dtbcT [192][8192] -> yT [64][8192] ----------
__global__ __launch_bounds__(256)
void scan_kernel(const float* __restrict__ dtbcT, float* __restrict__ yT)
{
    const int b = blockIdx.x >> 6;
    const int d = blockIdx.x & 63;
    const int t = threadIdx.x;
    const size_t col = (size_t)b * kSeq + t * 16;
    const float* dtp = dtbcT + (size_t)d         * 8192 + col;
    const float* Bp  = dtbcT + (size_t)(64 + d)  * 8192 + col;
    const float* Cp  = dtbcT + (size_t)(128 + d) * 8192 + col;

    float av[16], bv[16];
    float Acc = 1.f, Bcc = 0.f;
#pragma unroll
    for (int q = 0; q < 4; ++q) {
        float4 dv = *reinterpret_cast<const float4*>(dtp + q * 4);
        float4 Bv = *reinterpret_cast<const float4*>(Bp + q * 4);
        const float* dvp = (const float*)&dv;
        const float* bvp = (const float*)&Bv;
#pragma unroll
        for (int j = 0; j < 4; ++j) {
            const int i = q * 4 + j;
            float a  = 1.f - dvp[j];
            float bb = dvp[j] * bvp[j];
            av[i] = a; bv[i] = bb;
            Acc = a * Acc;
            Bcc = a * Bcc + bb;
        }
    }

    __shared__ float sA[256], sB[256];
    sA[t] = Acc; sB[t] = Bcc;
    __syncthreads();
    for (int off = 1; off < 256; off <<= 1) {
        float cA = sA[t], cB = sB[t];
        float pA = 1.f, pB = 0.f;
        if (t >= off) { pA = sA[t - off]; pB = sB[t - off]; }
        __syncthreads();
        if (t >= off) { sA[t] = cA * pA; sB[t] = cA * pB + cB; }
        __syncthreads();
    }

    float s = (t == 0) ? 0.f : sB[t - 1];
#pragma unroll
    for (int q = 0; q < 4; ++q) {
        float4 Cv = *reinterpret_cast<const float4*>(Cp + q * 4);
        const float* cvp = (const float*)&Cv;
        float4 ov;
        float* op = (float*)&ov;
#pragma unroll
        for (int j = 0; j < 4; ++j) {
            const int i = q * 4 + j;
            s = av[i] * s + bv[i];
            op[j] = cvp[j] * s;
        }
        *reinterpret_cast<float4*>(&yT[(size_t)d * 8192 + col + q * 4]) = ov;
    }
}

// ---------- LayerNorm over 64 states: yT [64][8192] -> ynb [8192][64] bf16 ----
__global__ __launch_bounds__(256)
void ln_kernel(const float* __restrict__ yT, u16* __restrict__ ynb)
{
    __shared__ float tile[64][132];
    __shared__ float ps[2][128], ps2[2][128];
    const int t  = threadIdx.x;
    const int r0 = blockIdx.x * 128;
    const int d  = t >> 2;
    const int cb = (t & 3) * 32;
#pragma unroll
    for (int j = 0; j < 8; ++j) {
        float4 v = *reinterpret_cast<const float4*>(&yT[(size_t)d * 8192 + r0 + cb + j * 4]);
        *reinterpret_cast<float4*>(&tile[d][cb + j * 4]) = v;
    }
    __syncthreads();
    const int r = t & 127, h = t >> 7;
    float s = 0.f, s2 = 0.f;
#pragma unroll
    for (int d2 = 0; d2 < 32; ++d2) {
        float v = tile[h * 32 + d2][r];
        s += v; s2 += v * v;
    }
    ps[h][r] = s; ps2[h][r] = s2;
    __syncthreads();
    const float S   = ps[0][r] + ps[1][r];
    const float S2  = ps2[0][r] + ps2[1][r];
    const float mu  = S * (1.f / 64.f);
    const float inv = rsqrtf(S2 * (1.f / 64.f) - mu * mu + 1e-5f);
    u16 o[32];
#pragma unroll
    for (int d2 = 0; d2 < 32; ++d2)
        o[d2] = f2bf((tile[h * 32 + d2][r] - mu) * inv);
#pragma unroll
    for (int q = 0; q < 4; ++q)
        *reinterpret_cast<uint4*>(&ynb[(size_t)(r0 + r) * 64 + h * 32 + q * 8]) =
            *reinterpret_cast<const uint4*>(&o[q * 8]);
}

}  // namespace

extern "C" void kernel_launch(void* const* d_in, const int* in_sizes, int n_in,
                              void* d_out, int out_size, void* d_ws, size_t ws_size,
                              hipStream_t stream)
{
    (void)in_sizes; (void)n_in; (void)out_size; (void)ws_size;
    const float* x     = (const float*)d_in[0];
    const float* W_in  = (const float*)d_in[1];
    const float* b_in  = (const float*)d_in[2];
    const float* cw    = (const float*)d_in[3];
    const float* cb    = (const float*)d_in[4];
    const float* W_dt  = (const float*)d_in[5];
    const float* b_dt  = (const float*)d_in[6];
    const float* W_B   = (const float*)d_in[7];
    const float* b_B   = (const float*)d_in[8];
    const float* W_C   = (const float*)d_in[9];
    const float* b_C   = (const float*)d_in[10];
    const float* W_si  = (const float*)d_in[11];
    const float* b_si  = (const float*)d_in[12];
    const float* Dv    = (const float*)d_in[13];
    const float* W_out = (const float*)d_in[14];
    const float* b_out = (const float*)d_in[15];
    float* out = (float*)d_out;

    char* ws = (char*)d_ws;
    u16*   xzb    = (u16*)  (ws);
    u16*   xb     = (u16*)  (ws + 67108864);
    u16*   xact   = (u16*)  (ws + 83886080);
    u16*   hb     = (u16*)  (ws + 117440512);
    float* dtbcT  = (float*)(ws + 150994944);
    float* yT     = (float*)(ws + 157286400);
    u16*   ynb    = (u16*)  (ws + 159383552);
    u16*   WinT   = (u16*)  (ws + 160432128);
    u16*   WoutT  = (u16*)  (ws + 168820736);
    u16*   WdtbcT = (u16*)  (ws + 173015040);
    u16*   WsiT   = (u16*)  (ws + 173801472);

    dim3 blk(256);
    dim3 blk512(512);

    // merged prep: x->bf16 + all weight transposes (one launch)
    prep_all<<<dim3(8192 + 4096 + 2048 + 384 + 128), blk, 0, stream>>>(
        x, xb, W_in, WinT, W_out, WoutT, W_dt, W_B, W_C, WdtbcT, W_si, WsiT);

    // xzb = bf16(x @ W_in + b_in)   [8192][4096]  (8-wave, BK=64 — measured best)
    gemm_mfma<128, 128, 64, 2, 4, 4, 1><<<dim3(32 * 64), blk512, 0, stream>>>(
        xb, WinT, b_in, nullptr, nullptr, nullptr, nullptr, xzb, 4096, 1024, 32);
    // xact = silu(causal_conv(xzb[:, :2048]))   (4 rows per thread)
    conv_silu<<<dim3(8192 / 4), blk, 0, stream>>>(xzb, cw, cb, xact);
    // dtbcT[192][8192] = [sigmoid(xact@W_dt+b) | xact@W_B+b | xact@W_C+b]^T  (BK=128)
    gemm_mfma<64, 64, 128, 2, 4, 4, 2><<<dim3(3 * 128), blk512, 0, stream>>>(
        xact, WdtbcT, b_dt, b_B, b_C, nullptr, nullptr, dtbcT, 192, 2048, 3);
    // yT[64][8192] = selective_scan(dt, B, C)   (coalesced transposed output)
    scan_kernel<<<dim3(128), blk, 0, stream>>>(dtbcT, yT);
    // ynb = bf16(layernorm over channels)   (tiled LDS-transpose)
    ln_kernel<<<dim3(64), blk, 0, stream>>>(yT, ynb);
    // hb = (ynb@W_si + b_si + D*xact) * sigmoid(gate)   (BK=64: K is 64)
    gemm_mfma<128, 128, 64, 2, 4, 4, 3><<<dim3(16 * 64), blk512, 0, stream>>>(
        ynb, WsiT, b_si, Dv, nullptr, xzb + 2048, xact, hb, 2048, 64, 16);
    // out = hb @ W_out + b_out   (8-wave, BK=128)
    gemm_mfma<128, 128, 128, 2, 4, 4, 0><<<dim3(8 * 64), blk512, 0, stream>>>(
        hb, WoutT, b_out, nullptr, nullptr, nullptr, nullptr, out, 1024, 2048, 8);
}

// Round 17
// 211.166 us; speedup vs baseline: 1.0992x; 1.0467x over previous
//
#include <hip/hip_runtime.h>
#include <hip/hip_bf16.h>
#include <math.h>

// SelectiveStateSpaceMixer — round 17: gemm_in -> BM=128,BN=256 with 64x64
// wave tiles (8 waves, FM=FN=4): cuts LDS read traffic from 0.75 to 0.5
// reads/MFMA (the measured 131 B/cyc LDS saturation). All else frozen at R16.
// ws layout (bytes):
//   xzb    bf16[8192][4096]  67108864 @ 0
//   xb     bf16[8192][1024]  16777216 @ 67108864
//   xact   bf16[8192][2048]  33554432 @ 83886080
//   hb     bf16[8192][2048]  33554432 @ 117440512
//   dtbcT  f32 [192][8192]    6291456 @ 150994944
//   yT     f32 [64][8192]     2097152 @ 157286400
//   ynb    bf16[8192][64]     1048576 @ 159383552
//   WinT   bf16[4096][1024]   8388608 @ 160432128
//   WoutT  bf16[1024][2048]   4194304 @ 168820736
//   WdtbcT bf16[192][2048]     786432 @ 173015040
//   WsiT   bf16[2048][64]      262144 @ 173801472   end 174063616

namespace {

typedef __bf16 bf16x8 __attribute__((ext_vector_type(8)));
typedef float  f32x4  __attribute__((ext_vector_type(4)));
typedef unsigned short u16;

constexpr int kSeq = 4096;

__device__ __forceinline__ float sigmoid_f(float x) { return 1.0f / (1.0f + expf(-x)); }
__device__ __forceinline__ u16   f2bf(float f) { __bf16 h = (__bf16)f; return __builtin_bit_cast(u16, h); }
__device__ __forceinline__ float bf2f(u16 u)   { return (float)__builtin_bit_cast(__bf16, u); }

// async global->LDS, 16B per lane (dest = wave-uniform base + lane*16)
__device__ __forceinline__ void gll16(const u16* g, u16* l) {
    __builtin_amdgcn_global_load_lds(
        (const __attribute__((address_space(1))) unsigned int*)g,
        (__attribute__((address_space(3))) unsigned int*)l,
        16, 0, 0);
}

// bijective XCD-aware block swizzle (m204)
__device__ __forceinline__ int xcd_swizzle(int lin, int nwg) {
    const int q = nwg >> 3, r = nwg & 7;
    const int xcd = lin & 7, idx = lin >> 3;
    return (xcd < r ? xcd * (q + 1) : r * (q + 1) + (xcd - r) * q) + idx;
}

// ---------- 32x32 tile transpose body: fp32 [R][C] -> bf16 [C][R] ----------
__device__ __forceinline__ void tr_body(float (*tile)[33],
                                        const float* __restrict__ in, u16* __restrict__ out,
                                        int R, int C, int r0, int c0, int t)
{
    const int lr = t >> 3, lc = (t & 7) * 4;
    float4 v = *reinterpret_cast<const float4*>(in + (size_t)(r0 + lr) * C + c0 + lc);
    tile[lr][lc + 0] = v.x; tile[lr][lc + 1] = v.y;
    tile[lr][lc + 2] = v.z; tile[lr][lc + 3] = v.w;
    __syncthreads();
    const int oc = t >> 3, orr = (t & 7) * 4;
    ushort4 o = make_ushort4(f2bf(tile[orr + 0][oc]), f2bf(tile[orr + 1][oc]),
                             f2bf(tile[orr + 2][oc]), f2bf(tile[orr + 3][oc]));
    *reinterpret_cast<ushort4*>(out + (size_t)(c0 + oc) * R + r0 + orr) = o;
}

// ---------- merged prep: x->bf16 + all weight transposes, one launch ----------
__global__ __launch_bounds__(256)
void prep_all(const float* __restrict__ x,    u16* __restrict__ xb,
              const float* __restrict__ Win,  u16* __restrict__ WinT,
              const float* __restrict__ Wout, u16* __restrict__ WoutT,
              const float* __restrict__ Wdt,  const float* __restrict__ WB,
              const float* __restrict__ WC,   u16* __restrict__ WdtbcT,
              const float* __restrict__ Wsi,  u16* __restrict__ WsiT)
{
    const int t = threadIdx.x;
    int b = blockIdx.x;
    if (b < 8192) {                       // convert x (2M ushort4)
        long i = (long)b * 256 + t;
        float4 v = reinterpret_cast<const float4*>(x)[i];
        ushort4 o = make_ushort4(f2bf(v.x), f2bf(v.y), f2bf(v.z), f2bf(v.w));
        reinterpret_cast<ushort4*>(xb)[i] = o;
        return;
    }
    __shared__ float tile[32][33];
    b -= 8192;
    if (b < 4096) {                       // W_in [1024][4096] -> [4096][1024]
        tr_body(tile, Win, WinT, 1024, 4096, (b / 128) * 32, (b % 128) * 32, t);
        return;
    }
    b -= 4096;
    if (b < 2048) {                       // W_out [2048][1024] -> [1024][2048]
        tr_body(tile, Wout, WoutT, 2048, 1024, (b % 64) * 32, (b / 64) * 32, t);
        return;
    }
    b -= 2048;
    if (b < 384) {                        // W_dt/W_B/W_C [2048][64] -> [64][2048]
        const int z = b / 128, rem = b % 128;
        const float* in = (z == 0) ? Wdt : (z == 1) ? WB : WC;
        u16* outp = WdtbcT + (size_t)z * 64 * 2048;
        tr_body(tile, in, outp, 2048, 64, (rem / 2) * 32, (rem % 2) * 32, t);
        return;
    }
    b -= 384;                             // W_si [64][2048] -> [2048][64]
    tr_body(tile, Wsi, WsiT, 64, 2048, (b % 2) * 32, (b / 2) * 32, t);
}

// ---------- 2-barrier MFMA GEMM: C[M][N] = A[M][K] @ Bt[N][K]^T ----------
// Templated BK (64 or 128), linear-LDS global_load_lds w16, both-sides XOR
// swizzle (16B-slot s of row r holds global slot s^(r&7)).
// EPI 0: fp32 out ldc=N     (gemm_out)
// EPI 1: bf16 out ldc=N     (gemm_in)
// EPI 2: fp32 TRANSPOSED out [N][8192]; bias b0|b1|b2 per 64-col; sigmoid col<64
// EPI 3: mix: bf16 out = (acc + b_si + D*xact) * sigmoid(gate)
template <int BM, int BN, int BK, int WM, int WN, int MINW, int EPI>
__global__ __launch_bounds__(WM * WN * 64, MINW)
void gemm_mfma(const u16* __restrict__ A, const u16* __restrict__ Bt,
               const float* __restrict__ b0, const float* __restrict__ b1,
               const float* __restrict__ b2,
               const u16* __restrict__ aux0, const u16* __restrict__ aux1,
               void* __restrict__ o0, int N, int K, int nbx)
{
    constexpr int WAVES = WM * WN;
    constexpr int FM = BM / WM / 16, FN = BN / WN / 16;
    constexpr int LPR = BK / 8;            // lanes per LDS row (staging)
    constexpr int RPC = 64 / LPR;          // rows per 1KB staging chunk
    constexpr int CA  = BM * BK / 512 / WAVES;   // A chunks per wave
    constexpr int CB  = BN * BK / 512 / WAVES;   // B chunks per wave
    constexpr int NKK = BK / 32;           // MFMA K-subtiles per step
    __shared__ __align__(16) u16 As[BM][BK];
    __shared__ __align__(16) u16 Bs[BN][BK];

    const int tid  = threadIdx.x;
    const int lane = tid & 63;
    const int wid  = tid >> 6;
    const int wr   = (wid / WN) * (BM / WM);
    const int wc   = (wid % WN) * (BN / WN);
    const int swz  = xcd_swizzle(blockIdx.x, gridDim.x);
    const int row0 = (swz / nbx) * BM;
    const int col0 = (swz % nbx) * BN;

    const int srow = lane / LPR;           // row within chunk
    const int slot = lane % LPR;           // 16B slot within row
    const int fr   = lane & 15;
    const int fq   = lane >> 4;

    f32x4 acc[FM][FN];
#pragma unroll
    for (int m = 0; m < FM; ++m)
#pragma unroll
        for (int n = 0; n < FN; ++n) acc[m][n] = (f32x4){0.f, 0.f, 0.f, 0.f};

    for (int k0 = 0; k0 < K; k0 += BK) {
#pragma unroll
        for (int i = 0; i < CA; ++i) {
            const int c   = wid * CA + i;
            const int row = c * RPC + srow;
            const int sc  = (slot ^ (row & 7)) * 8;   // pre-swizzled global col
            gll16(A + (size_t)(row0 + row) * K + k0 + sc,
                  &As[0][0] + c * 512 + lane * 8);
        }
#pragma unroll
        for (int i = 0; i < CB; ++i) {
            const int c   = wid * CB + i;
            const int row = c * RPC + srow;
            const int sc  = (slot ^ (row & 7)) * 8;
            gll16(Bt + (size_t)(col0 + row) * K + k0 + sc,
                  &Bs[0][0] + c * 512 + lane * 8);
        }
        __syncthreads();
#pragma unroll
        for (int kk = 0; kk < NKK; ++kk) {
            bf16x8 af[FM], bg[FN];
#pragma unroll
            for (int m = 0; m < FM; ++m) {
                const int rr = wr + m * 16 + fr;
                af[m] = *reinterpret_cast<const bf16x8*>(
                    &As[rr][((kk * 4 + fq) ^ (rr & 7)) * 8]);
            }
#pragma unroll
            for (int n = 0; n < FN; ++n) {
                const int rr = wc + n * 16 + fr;
                bg[n] = *reinterpret_cast<const bf16x8*>(
                    &Bs[rr][((kk * 4 + fq) ^ (rr & 7)) * 8]);
            }
#pragma unroll
            for (int m = 0; m < FM; ++m)
#pragma unroll
                for (int n = 0; n < FN; ++n)
                    acc[m][n] = __builtin_amdgcn_mfma_f32_16x16x32_bf16(af[m], bg[n], acc[m][n], 0, 0, 0);
        }
        __syncthreads();
    }

#pragma unroll
    for (int m = 0; m < FM; ++m) {
#pragma unroll
        for (int n = 0; n < FN; ++n) {
            const int gc  = col0 + wc + n * 16 + fr;
            const int gr0 = row0 + wr + m * 16 + fq * 4;
            if constexpr (EPI == 2) {
                float4 vv;
                float* vp = (float*)&vv;
#pragma unroll
                for (int j = 0; j < 4; ++j) {
                    float bb = (gc < 64) ? b0[gc] : (gc < 128) ? b1[gc - 64] : b2[gc - 128];
                    float v = acc[m][n][j] + bb;
                    if (gc < 64) v = sigmoid_f(v);
                    vp[j] = v;
                }
                *reinterpret_cast<float4*>(&((float*)o0)[(size_t)gc * 8192 + gr0]) = vv;
            } else {
#pragma unroll
                for (int j = 0; j < 4; ++j) {
                    const int gr = gr0 + j;
                    float v = acc[m][n][j];
                    if constexpr (EPI == 0) {
                        ((float*)o0)[(size_t)gr * N + gc] = v + b0[gc];
                    } else if constexpr (EPI == 1) {
                        ((u16*)o0)[(size_t)gr * N + gc] = f2bf(v + b0[gc]);
                    } else {  // EPI 3: mix
                        const size_t p = (size_t)gr * 2048 + gc;
                        float g  = bf2f(aux0[(size_t)gr * 4096 + gc]);   // gate
                        float xa = bf2f(aux1[p]);                        // xact
                        v = v + b0[gc] + b1[gc] * xa;
                        ((u16*)o0)[p] = f2bf(v * sigmoid_f(g));
                    }
                }
            }
        }
    }
    (void)b1; (void)b2; (void)aux0; (void)aux1;
}

// ---------- depthwise causal conv (K=3) + bias + SiLU, 4 rows/thread ----------
__global__ __launch_bounds__(256)
void conv_silu(const u16* __restrict__ xz, const float* __restrict__ cw,
               const float* __restrict__ cb, u16* __restrict__ xact)
{
    const int    c0 = threadIdx.x * 8;                 // 0..2040 (full row width)
    const size_t r0 = (size_t)blockIdx.x * 4;          // 4 consecutive seq rows
    const int    s0 = (int)(r0 & (kSeq - 1));          // multiple of 4
    const u16*   p  = xz + r0 * 4096 + c0;

    u16 X[6][8];                                       // rows s0-2 .. s0+3
#pragma unroll
    for (int k = 0; k < 6; ++k) {
        if (k >= 2 || s0 != 0) {
            *reinterpret_cast<uint4*>(X[k]) =
                *reinterpret_cast<const uint4*>(p + ((long)k - 2) * 4096);
        } else {
            *reinterpret_cast<uint4*>(X[k]) = make_uint4(0, 0, 0, 0);
        }
    }
    float w0[8], w1[8], w2[8], bias[8];
#pragma unroll
    for (int j = 0; j < 8; ++j) {
        const int c = c0 + j;
        w0[j] = cw[c * 3 + 0]; w1[j] = cw[c * 3 + 1];
        w2[j] = cw[c * 3 + 2]; bias[j] = cb[c];
    }
#pragma unroll
    for (int i = 0; i < 4; ++i) {
        u16 O[8];
#pragma unroll
        for (int j = 0; j < 8; ++j) {
            float v = bf2f(X[i][j]) * w0[j] + bf2f(X[i + 1][j]) * w1[j]
                    + bf2f(X[i + 2][j]) * w2[j] + bias[j];
            O[j] = f2bf(v * sigmoid_f(v));
        }
        *reinterpret_cast<uint4*>(xact + (r0 + i) * 2048 + c0) =
            *reinterpret_cast<uint4*>(O);
    }
}

// ---------- selective scan over dtbcT [192][8192] -> yT [64][8192] ----------
__global__ __launch_bounds__(256)
void scan_kernel(const float* __restrict__ dtbcT, float* __restrict__ yT)
{
    const int b = blockIdx.x >> 6;
    const int d = blockIdx.x & 63;
    const int t = threadIdx.x;
    const size_t col = (size_t)b * kSeq + t * 16;
    const float* dtp = dtbcT + (size_t)d         * 8192 + col;
    const float* Bp  = dtbcT + (size_t)(64 + d)  * 8192 + col;
    const float* Cp  = dtbcT + (size_t)(128 + d) * 8192 + col;

    float av[16], bv[16];
    float Acc = 1.f, Bcc = 0.f;
#pragma unroll
    for (int q = 0; q < 4; ++q) {
        float4 dv = *reinterpret_cast<const float4*>(dtp + q * 4);
        float4 Bv = *reinterpret_cast<const float4*>(Bp + q * 4);
        const float* dvp = (const float*)&dv;
        const float* bvp = (const float*)&Bv;
#pragma unroll
        for (int j = 0; j < 4; ++j) {
            const int i = q * 4 + j;
            float a  = 1.f - dvp[j];
            float bb = dvp[j] * bvp[j];
            av[i] = a; bv[i] = bb;
            Acc = a * Acc;
            Bcc = a * Bcc + bb;
        }
    }

    __shared__ float sA[256], sB[256];
    sA[t] = Acc; sB[t] = Bcc;
    __syncthreads();
    for (int off = 1; off < 256; off <<= 1) {
        float cA = sA[t], cB = sB[t];
        float pA = 1.f, pB = 0.f;
        if (t >= off) { pA = sA[t - off]; pB = sB[t - off]; }
        __syncthreads();
        if (t >= off) { sA[t] = cA * pA; sB[t] = cA * pB + cB; }
        __syncthreads();
    }

    float s = (t == 0) ? 0.f : sB[t - 1];
#pragma unroll
    for (int q = 0; q < 4; ++q) {
        float4 Cv = *reinterpret_cast<const float4*>(Cp + q * 4);
        const float* cvp = (const float*)&Cv;
        float4 ov;
        float* op = (float*)&ov;
#pragma unroll
        for (int j = 0; j < 4; ++j) {
            const int i = q * 4 + j;
            s = av[i] * s + bv[i];
            op[j] = cvp[j] * s;
        }
        *reinterpret_cast<float4*>(&yT[(size_t)d * 8192 + col + q * 4]) = ov;
    }
}

// ---------- LayerNorm over 64 states: yT [64][8192] -> ynb [8192][64] bf16 ----
__global__ __launch_bounds__(256)
void ln_kernel(const float* __restrict__ yT, u16* __restrict__ ynb)
{
    __shared__ float tile[64][132];
    __shared__ float ps[2][128], ps2[2][128];
    const int t  = threadIdx.x;
    const int r0 = blockIdx.x * 128;
    const int d  = t >> 2;
    const int cb = (t & 3) * 32;
#pragma unroll
    for (int j = 0; j < 8; ++j) {
        float4 v = *reinterpret_cast<const float4*>(&yT[(size_t)d * 8192 + r0 + cb + j * 4]);
        *reinterpret_cast<float4*>(&tile[d][cb + j * 4]) = v;
    }
    __syncthreads();
    const int r = t & 127, h = t >> 7;
    float s = 0.f, s2 = 0.f;
#pragma unroll
    for (int d2 = 0; d2 < 32; ++d2) {
        float v = tile[h * 32 + d2][r];
        s += v; s2 += v * v;
    }
    ps[h][r] = s; ps2[h][r] = s2;
    __syncthreads();
    const float S   = ps[0][r] + ps[1][r];
    const float S2  = ps2[0][r] + ps2[1][r];
    const float mu  = S * (1.f / 64.f);
    const float inv = rsqrtf(S2 * (1.f / 64.f) - mu * mu + 1e-5f);
    u16 o[32];
#pragma unroll
    for (int d2 = 0; d2 < 32; ++d2)
        o[d2] = f2bf((tile[h * 32 + d2][r] - mu) * inv);
#pragma unroll
    for (int q = 0; q < 4; ++q)
        *reinterpret_cast<uint4*>(&ynb[(size_t)(r0 + r) * 64 + h * 32 + q * 8]) =
            *reinterpret_cast<const uint4*>(&o[q * 8]);
}

}  // namespace

extern "C" void kernel_launch(void* const* d_in, const int* in_sizes, int n_in,
                              void* d_out, int out_size, void* d_ws, size_t ws_size,
                              hipStream_t stream)
{
    (void)in_sizes; (void)n_in; (void)out_size; (void)ws_size;
    const float* x     = (const float*)d_in[0];
    const float* W_in  = (const float*)d_in[1];
    const float* b_in  = (const float*)d_in[2];
    const float* cw    = (const float*)d_in[3];
    const float* cb    = (const float*)d_in[4];
    const float* W_dt  = (const float*)d_in[5];
    const float* b_dt  = (const float*)d_in[6];
    const float* W_B   = (const float*)d_in[7];
    const float* b_B   = (const float*)d_in[8];
    const float* W_C   = (const float*)d_in[9];
    const float* b_C   = (const float*)d_in[10];
    const float* W_si  = (const float*)d_in[11];
    const float* b_si  = (const float*)d_in[12];
    const float* Dv    = (const float*)d_in[13];
    const float* W_out = (const float*)d_in[14];
    const float* b_out = (const float*)d_in[15];
    float* out = (float*)d_out;

    char* ws = (char*)d_ws;
    u16*   xzb    = (u16*)  (ws);
    u16*   xb     = (u16*)  (ws + 67108864);
    u16*   xact   = (u16*)  (ws + 83886080);
    u16*   hb     = (u16*)  (ws + 117440512);
    float* dtbcT  = (float*)(ws + 150994944);
    float* yT     = (float*)(ws + 157286400);
    u16*   ynb    = (u16*)  (ws + 159383552);
    u16*   WinT   = (u16*)  (ws + 160432128);
    u16*   WoutT  = (u16*)  (ws + 168820736);
    u16*   WdtbcT = (u16*)  (ws + 173015040);
    u16*   WsiT   = (u16*)  (ws + 173801472);

    dim3 blk(256);
    dim3 blk512(512);

    // merged prep: x->bf16 + all weight transposes (one launch)
    prep_all<<<dim3(8192 + 4096 + 2048 + 384 + 128), blk, 0, stream>>>(
        x, xb, W_in, WinT, W_out, WoutT, W_dt, W_B, W_C, WdtbcT, W_si, WsiT);

    // xzb = bf16(x @ W_in + b_in)   [8192][4096]
    // NEW: BM=128,BN=256, 64x64 wave tiles -> 0.5 LDS reads/MFMA
    gemm_mfma<128, 256, 64, 2, 4, 4, 1><<<dim3(64 * 16), blk512, 0, stream>>>(
        xb, WinT, b_in, nullptr, nullptr, nullptr, nullptr, xzb, 4096, 1024, 16);
    // xact = silu(causal_conv(xzb[:, :2048]))   (4 rows per thread)
    conv_silu<<<dim3(8192 / 4), blk, 0, stream>>>(xzb, cw, cb, xact);
    // dtbcT[192][8192] = [sigmoid(xact@W_dt+b) | xact@W_B+b | xact@W_C+b]^T  (BK=128)
    gemm_mfma<64, 64, 128, 2, 4, 4, 2><<<dim3(3 * 128), blk512, 0, stream>>>(
        xact, WdtbcT, b_dt, b_B, b_C, nullptr, nullptr, dtbcT, 192, 2048, 3);
    // yT[64][8192] = selective_scan(dt, B, C)
    scan_kernel<<<dim3(128), blk, 0, stream>>>(dtbcT, yT);
    // ynb = bf16(layernorm over channels)
    ln_kernel<<<dim3(64), blk, 0, stream>>>(yT, ynb);
    // hb = (ynb@W_si + b_si + D*xact) * sigmoid(gate)   (BK=64: K is 64)
    gemm_mfma<128, 128, 64, 2, 4, 4, 3><<<dim3(16 * 64), blk512, 0, stream>>>(
        ynb, WsiT, b_si, Dv, nullptr, xzb + 2048, xact, hb, 2048, 64, 16);
    // out = hb @ W_out + b_out   (R14-proven: 128x128 BK=128)
    gemm_mfma<128, 128, 128, 2, 4, 4, 0><<<dim3(8 * 64), blk512, 0, stream>>>(
        hb, WoutT, b_out, nullptr, nullptr, nullptr, nullptr, out, 1024, 2048, 8);
}

// Round 18
// 204.756 us; speedup vs baseline: 1.1336x; 1.0313x over previous
//
#include <hip/hip_runtime.h>
#include <hip/hip_bf16.h>
#include <math.h>

// SelectiveStateSpaceMixer — round 18: R17 + 64x64 wave tiles on gemm_out/mix
// via 4-wave 128x128 blocks (0.5 LDS reads/MFMA, 4 blocks/CU co-residency).
// gemm_in stays at R17's measured-best 8-wave 128x256.
// ws layout (bytes):
//   xzb    bf16[8192][4096]  67108864 @ 0
//   xb     bf16[8192][1024]  16777216 @ 67108864
//   xact   bf16[8192][2048]  33554432 @ 83886080
//   hb     bf16[8192][2048]  33554432 @ 117440512
//   dtbcT  f32 [192][8192]    6291456 @ 150994944
//   yT     f32 [64][8192]     2097152 @ 157286400
//   ynb    bf16[8192][64]     1048576 @ 159383552
//   WinT   bf16[4096][1024]   8388608 @ 160432128
//   WoutT  bf16[1024][2048]   4194304 @ 168820736
//   WdtbcT bf16[192][2048]     786432 @ 173015040
//   WsiT   bf16[2048][64]      262144 @ 173801472   end 174063616

namespace {

typedef __bf16 bf16x8 __attribute__((ext_vector_type(8)));
typedef float  f32x4  __attribute__((ext_vector_type(4)));
typedef unsigned short u16;

constexpr int kSeq = 4096;

__device__ __forceinline__ float sigmoid_f(float x) { return 1.0f / (1.0f + expf(-x)); }
__device__ __forceinline__ u16   f2bf(float f) { __bf16 h = (__bf16)f; return __builtin_bit_cast(u16, h); }
__device__ __forceinline__ float bf2f(u16 u)   { return (float)__builtin_bit_cast(__bf16, u); }

// async global->LDS, 16B per lane (dest = wave-uniform base + lane*16)
__device__ __forceinline__ void gll16(const u16* g, u16* l) {
    __builtin_amdgcn_global_load_lds(
        (const __attribute__((address_space(1))) unsigned int*)g,
        (__attribute__((address_space(3))) unsigned int*)l,
        16, 0, 0);
}

// bijective XCD-aware block swizzle (m204)
__device__ __forceinline__ int xcd_swizzle(int lin, int nwg) {
    const int q = nwg >> 3, r = nwg & 7;
    const int xcd = lin & 7, idx = lin >> 3;
    return (xcd < r ? xcd * (q + 1) : r * (q + 1) + (xcd - r) * q) + idx;
}

// ---------- 32x32 tile transpose body: fp32 [R][C] -> bf16 [C][R] ----------
__device__ __forceinline__ void tr_body(float (*tile)[33],
                                        const float* __restrict__ in, u16* __restrict__ out,
                                        int R, int C, int r0, int c0, int t)
{
    const int lr = t >> 3, lc = (t & 7) * 4;
    float4 v = *reinterpret_cast<const float4*>(in + (size_t)(r0 + lr) * C + c0 + lc);
    tile[lr][lc + 0] = v.x; tile[lr][lc + 1] = v.y;
    tile[lr][lc + 2] = v.z; tile[lr][lc + 3] = v.w;
    __syncthreads();
    const int oc = t >> 3, orr = (t & 7) * 4;
    ushort4 o = make_ushort4(f2bf(tile[orr + 0][oc]), f2bf(tile[orr + 1][oc]),
                             f2bf(tile[orr + 2][oc]), f2bf(tile[orr + 3][oc]));
    *reinterpret_cast<ushort4*>(out + (size_t)(c0 + oc) * R + r0 + orr) = o;
}

// ---------- merged prep: x->bf16 + all weight transposes, one launch ----------
__global__ __launch_bounds__(256)
void prep_all(const float* __restrict__ x,    u16* __restrict__ xb,
              const float* __restrict__ Win,  u16* __restrict__ WinT,
              const float* __restrict__ Wout, u16* __restrict__ WoutT,
              const float* __restrict__ Wdt,  const float* __restrict__ WB,
              const float* __restrict__ WC,   u16* __restrict__ WdtbcT,
              const float* __restrict__ Wsi,  u16* __restrict__ WsiT)
{
    const int t = threadIdx.x;
    int b = blockIdx.x;
    if (b < 8192) {                       // convert x (2M ushort4)
        long i = (long)b * 256 + t;
        float4 v = reinterpret_cast<const float4*>(x)[i];
        ushort4 o = make_ushort4(f2bf(v.x), f2bf(v.y), f2bf(v.z), f2bf(v.w));
        reinterpret_cast<ushort4*>(xb)[i] = o;
        return;
    }
    __shared__ float tile[32][33];
    b -= 8192;
    if (b < 4096) {                       // W_in [1024][4096] -> [4096][1024]
        tr_body(tile, Win, WinT, 1024, 4096, (b / 128) * 32, (b % 128) * 32, t);
        return;
    }
    b -= 4096;
    if (b < 2048) {                       // W_out [2048][1024] -> [1024][2048]
        tr_body(tile, Wout, WoutT, 2048, 1024, (b % 64) * 32, (b / 64) * 32, t);
        return;
    }
    b -= 2048;
    if (b < 384) {                        // W_dt/W_B/W_C [2048][64] -> [64][2048]
        const int z = b / 128, rem = b % 128;
        const float* in = (z == 0) ? Wdt : (z == 1) ? WB : WC;
        u16* outp = WdtbcT + (size_t)z * 64 * 2048;
        tr_body(tile, in, outp, 2048, 64, (rem / 2) * 32, (rem % 2) * 32, t);
        return;
    }
    b -= 384;                             // W_si [64][2048] -> [2048][64]
    tr_body(tile, Wsi, WsiT, 64, 2048, (b % 2) * 32, (b / 2) * 32, t);
}

// ---------- 2-barrier MFMA GEMM: C[M][N] = A[M][K] @ Bt[N][K]^T ----------
// Templated BK (64 or 128), linear-LDS global_load_lds w16, both-sides XOR
// swizzle (16B-slot s of row r holds global slot s^(r&7)).
// EPI 0: fp32 out ldc=N     (gemm_out)
// EPI 1: bf16 out ldc=N     (gemm_in)
// EPI 2: fp32 TRANSPOSED out [N][8192]; bias b0|b1|b2 per 64-col; sigmoid col<64
// EPI 3: mix: bf16 out = (acc + b_si + D*xact) * sigmoid(gate)
template <int BM, int BN, int BK, int WM, int WN, int MINW, int EPI>
__global__ __launch_bounds__(WM * WN * 64, MINW)
void gemm_mfma(const u16* __restrict__ A, const u16* __restrict__ Bt,
               const float* __restrict__ b0, const float* __restrict__ b1,
               const float* __restrict__ b2,
               const u16* __restrict__ aux0, const u16* __restrict__ aux1,
               void* __restrict__ o0, int N, int K, int nbx)
{
    constexpr int WAVES = WM * WN;
    constexpr int FM = BM / WM / 16, FN = BN / WN / 16;
    constexpr int LPR = BK / 8;            // lanes per LDS row (staging)
    constexpr int RPC = 64 / LPR;          // rows per 1KB staging chunk
    constexpr int CA  = BM * BK / 512 / WAVES;   // A chunks per wave
    constexpr int CB  = BN * BK / 512 / WAVES;   // B chunks per wave
    constexpr int NKK = BK / 32;           // MFMA K-subtiles per step
    __shared__ __align__(16) u16 As[BM][BK];
    __shared__ __align__(16) u16 Bs[BN][BK];

    const int tid  = threadIdx.x;
    const int lane = tid & 63;
    const int wid  = tid >> 6;
    const int wr   = (wid / WN) * (BM / WM);
    const int wc   = (wid % WN) * (BN / WN);
    const int swz  = xcd_swizzle(blockIdx.x, gridDim.x);
    const int row0 = (swz / nbx) * BM;
    const int col0 = (swz % nbx) * BN;

    const int srow = lane / LPR;           // row within chunk
    const int slot = lane % LPR;           // 16B slot within row
    const int fr   = lane & 15;
    const int fq   = lane >> 4;

    f32x4 acc[FM][FN];
#pragma unroll
    for (int m = 0; m < FM; ++m)
#pragma unroll
        for (int n = 0; n < FN; ++n) acc[m][n] = (f32x4){0.f, 0.f, 0.f, 0.f};

    for (int k0 = 0; k0 < K; k0 += BK) {
#pragma unroll
        for (int i = 0; i < CA; ++i) {
            const int c   = wid * CA + i;
            const int row = c * RPC + srow;
            const int sc  = (slot ^ (row & 7)) * 8;   // pre-swizzled global col
            gll16(A + (size_t)(row0 + row) * K + k0 + sc,
                  &As[0][0] + c * 512 + lane * 8);
        }
#pragma unroll
        for (int i = 0; i < CB; ++i) {
            const int c   = wid * CB + i;
            const int row = c * RPC + srow;
            const int sc  = (slot ^ (row & 7)) * 8;
            gll16(Bt + (size_t)(col0 + row) * K + k0 + sc,
                  &Bs[0][0] + c * 512 + lane * 8);
        }
        __syncthreads();
#pragma unroll
        for (int kk = 0; kk < NKK; ++kk) {
            bf16x8 af[FM], bg[FN];
#pragma unroll
            for (int m = 0; m < FM; ++m) {
                const int rr = wr + m * 16 + fr;
                af[m] = *reinterpret_cast<const bf16x8*>(
                    &As[rr][((kk * 4 + fq) ^ (rr & 7)) * 8]);
            }
#pragma unroll
            for (int n = 0; n < FN; ++n) {
                const int rr = wc + n * 16 + fr;
                bg[n] = *reinterpret_cast<const bf16x8*>(
                    &Bs[rr][((kk * 4 + fq) ^ (rr & 7)) * 8]);
            }
#pragma unroll
            for (int m = 0; m < FM; ++m)
#pragma unroll
                for (int n = 0; n < FN; ++n)
                    acc[m][n] = __builtin_amdgcn_mfma_f32_16x16x32_bf16(af[m], bg[n], acc[m][n], 0, 0, 0);
        }
        __syncthreads();
    }

#pragma unroll
    for (int m = 0; m < FM; ++m) {
#pragma unroll
        for (int n = 0; n < FN; ++n) {
            const int gc  = col0 + wc + n * 16 + fr;
            const int gr0 = row0 + wr + m * 16 + fq * 4;
            if constexpr (EPI == 2) {
                float4 vv;
                float* vp = (float*)&vv;
#pragma unroll
                for (int j = 0; j < 4; ++j) {
                    float bb = (gc < 64) ? b0[gc] : (gc < 128) ? b1[gc - 64] : b2[gc - 128];
                    float v = acc[m][n][j] + bb;
                    if (gc < 64) v = sigmoid_f(v);
                    vp[j] = v;
                }
                *reinterpret_cast<float4*>(&((float*)o0)[(size_t)gc * 8192 + gr0]) = vv;
            } else {
#pragma unroll
                for (int j = 0; j < 4; ++j) {
                    const int gr = gr0 + j;
                    float v = acc[m][n][j];
                    if constexpr (EPI == 0) {
                        ((float*)o0)[(size_t)gr * N + gc] = v + b0[gc];
                    } else if constexpr (EPI == 1) {
                        ((u16*)o0)[(size_t)gr * N + gc] = f2bf(v + b0[gc]);
                    } else {  // EPI 3: mix
                        const size_t p = (size_t)gr * 2048 + gc;
                        float g  = bf2f(aux0[(size_t)gr * 4096 + gc]);   // gate
                        float xa = bf2f(aux1[p]);                        // xact
                        v = v + b0[gc] + b1[gc] * xa;
                        ((u16*)o0)[p] = f2bf(v * sigmoid_f(g));
                    }
                }
            }
        }
    }
    (void)b1; (void)b2; (void)aux0; (void)aux1;
}

// ---------- depthwise causal conv (K=3) + bias + SiLU, 4 rows/thread ----------
__global__ __launch_bounds__(256)
void conv_silu(const u16* __restrict__ xz, const float* __restrict__ cw,
               const float* __restrict__ cb, u16* __restrict__ xact)
{
    const int    c0 = threadIdx.x * 8;                 // 0..2040 (full row width)
    const size_t r0 = (size_t)blockIdx.x * 4;          // 4 consecutive seq rows
    const int    s0 = (int)(r0 & (kSeq - 1));          // multiple of 4
    const u16*   p  = xz + r0 * 4096 + c0;

    u16 X[6][8];                                       // rows s0-2 .. s0+3
#pragma unroll
    for (int k = 0; k < 6; ++k) {
        if (k >= 2 || s0 != 0) {
            *reinterpret_cast<uint4*>(X[k]) =
                *reinterpret_cast<const uint4*>(p + ((long)k - 2) * 4096);
        } else {
            *reinterpret_cast<uint4*>(X[k]) = make_uint4(0, 0, 0, 0);
        }
    }
    float w0[8], w1[8], w2[8], bias[8];
#pragma unroll
    for (int j = 0; j < 8; ++j) {
        const int c = c0 + j;
        w0[j] = cw[c * 3 + 0]; w1[j] = cw[c * 3 + 1];
        w2[j] = cw[c * 3 + 2]; bias[j] = cb[c];
    }
#pragma unroll
    for (int i = 0; i < 4; ++i) {
        u16 O[8];
#pragma unroll
        for (int j = 0; j < 8; ++j) {
            float v = bf2f(X[i][j]) * w0[j] + bf2f(X[i + 1][j]) * w1[j]
                    + bf2f(X[i + 2][j]) * w2[j] + bias[j];
            O[j] = f2bf(v * sigmoid_f(v));
        }
        *reinterpret_cast<uint4*>(xact + (r0 + i) * 2048 + c0) =
            *reinterpret_cast<uint4*>(O);
    }
}

// ---------- selective scan over dtbcT [192][8192] -> yT [64][8192] ----------
__global__ __launch_bounds__(256)
void scan_kernel(const float* __restrict__ dtbcT, float* __restrict__ yT)
{
    const int b = blockIdx.x >> 6;
    const int d = blockIdx.x & 63;
    const int t = threadIdx.x;
    const size_t col = (size_t)b * kSeq + t * 16;
    const float* dtp = dtbcT + (size_t)d         * 8192 + col;
    const float* Bp  = dtbcT + (size_t)(64 + d)  * 8192 + col;
    const float* Cp  = dtbcT + (size_t)(128 + d) * 8192 + col;

    float av[16], bv[16];
    float Acc = 1.f, Bcc = 0.f;
#pragma unroll
    for (int q = 0; q < 4; ++q) {
        float4 dv = *reinterpret_cast<const float4*>(dtp + q * 4);
        float4 Bv = *reinterpret_cast<const float4*>(Bp + q * 4);
        const float* dvp = (const float*)&dv;
        const float* bvp = (const float*)&Bv;
#pragma unroll
        for (int j = 0; j < 4; ++j) {
            const int i = q * 4 + j;
            float a  = 1.f - dvp[j];
            float bb = dvp[j] * bvp[j];
            av[i] = a; bv[i] = bb;
            Acc = a * Acc;
            Bcc = a * Bcc + bb;
        }
    }

    __shared__ float sA[256], sB[256];
    sA[t] = Acc; sB[t] = Bcc;
    __syncthreads();
    for (int off = 1; off < 256; off <<= 1) {
        float cA = sA[t], cB = sB[t];
        float pA = 1.f, pB = 0.f;
        if (t >= off) { pA = sA[t - off]; pB = sB[t - off]; }
        __syncthreads();
        if (t >= off) { sA[t] = cA * pA; sB[t] = cA * pB + cB; }
        __syncthreads();
    }

    float s = (t == 0) ? 0.f : sB[t - 1];
#pragma unroll
    for (int q = 0; q < 4; ++q) {
        float4 Cv = *reinterpret_cast<const float4*>(Cp + q * 4);
        const float* cvp = (const float*)&Cv;
        float4 ov;
        float* op = (float*)&ov;
#pragma unroll
        for (int j = 0; j < 4; ++j) {
            const int i = q * 4 + j;
            s = av[i] * s + bv[i];
            op[j] = cvp[j] * s;
        }
        *reinterpret_cast<float4*>(&yT[(size_t)d * 8192 + col + q * 4]) = ov;
    }
}

// ---------- LayerNorm over 64 states: yT [64][8192] -> ynb [8192][64] bf16 ----
__global__ __launch_bounds__(256)
void ln_kernel(const float* __restrict__ yT, u16* __restrict__ ynb)
{
    __shared__ float tile[64][132];
    __shared__ float ps[2][128], ps2[2][128];
    const int t  = threadIdx.x;
    const int r0 = blockIdx.x * 128;
    const int d  = t >> 2;
    const int cb = (t & 3) * 32;
#pragma unroll
    for (int j = 0; j < 8; ++j) {
        float4 v = *reinterpret_cast<const float4*>(&yT[(size_t)d * 8192 + r0 + cb + j * 4]);
        *reinterpret_cast<float4*>(&tile[d][cb + j * 4]) = v;
    }
    __syncthreads();
    const int r = t & 127, h = t >> 7;
    float s = 0.f, s2 = 0.f;
#pragma unroll
    for (int d2 = 0; d2 < 32; ++d2) {
        float v = tile[h * 32 + d2][r];
        s += v; s2 += v * v;
    }
    ps[h][r] = s; ps2[h][r] = s2;
    __syncthreads();
    const float S   = ps[0][r] + ps[1][r];
    const float S2  = ps2[0][r] + ps2[1][r];
    const float mu  = S * (1.f / 64.f);
    const float inv = rsqrtf(S2 * (1.f / 64.f) - mu * mu + 1e-5f);
    u16 o[32];
#pragma unroll
    for (int d2 = 0; d2 < 32; ++d2)
        o[d2] = f2bf((tile[h * 32 + d2][r] - mu) * inv);
#pragma unroll
    for (int q = 0; q < 4; ++q)
        *reinterpret_cast<uint4*>(&ynb[(size_t)(r0 + r) * 64 + h * 32 + q * 8]) =
            *reinterpret_cast<const uint4*>(&o[q * 8]);
}

}  // namespace

extern "C" void kernel_launch(void* const* d_in, const int* in_sizes, int n_in,
                              void* d_out, int out_size, void* d_ws, size_t ws_size,
                              hipStream_t stream)
{
    (void)in_sizes; (void)n_in; (void)out_size; (void)ws_size;
    const float* x     = (const float*)d_in[0];
    const float* W_in  = (const float*)d_in[1];
    const float* b_in  = (const float*)d_in[2];
    const float* cw    = (const float*)d_in[3];
    const float* cb    = (const float*)d_in[4];
    const float* W_dt  = (const float*)d_in[5];
    const float* b_dt  = (const float*)d_in[6];
    const float* W_B   = (const float*)d_in[7];
    const float* b_B   = (const float*)d_in[8];
    const float* W_C   = (const float*)d_in[9];
    const float* b_C   = (const float*)d_in[10];
    const float* W_si  = (const float*)d_in[11];
    const float* b_si  = (const float*)d_in[12];
    const float* Dv    = (const float*)d_in[13];
    const float* W_out = (const float*)d_in[14];
    const float* b_out = (const float*)d_in[15];
    float* out = (float*)d_out;

    char* ws = (char*)d_ws;
    u16*   xzb    = (u16*)  (ws);
    u16*   xb     = (u16*)  (ws + 67108864);
    u16*   xact   = (u16*)  (ws + 83886080);
    u16*   hb     = (u16*)  (ws + 117440512);
    float* dtbcT  = (float*)(ws + 150994944);
    float* yT     = (float*)(ws + 157286400);
    u16*   ynb    = (u16*)  (ws + 159383552);
    u16*   WinT   = (u16*)  (ws + 160432128);
    u16*   WoutT  = (u16*)  (ws + 168820736);
    u16*   WdtbcT = (u16*)  (ws + 173015040);
    u16*   WsiT   = (u16*)  (ws + 173801472);

    dim3 blk(256);
    dim3 blk512(512);

    // merged prep: x->bf16 + all weight transposes (one launch)
    prep_all<<<dim3(8192 + 4096 + 2048 + 384 + 128), blk, 0, stream>>>(
        x, xb, W_in, WinT, W_out, WoutT, W_dt, W_B, W_C, WdtbcT, W_si, WsiT);

    // xzb = bf16(x @ W_in + b_in)   [8192][4096]  (R17-proven 8-wave 128x256)
    gemm_mfma<128, 256, 64, 2, 4, 4, 1><<<dim3(64 * 16), blk512, 0, stream>>>(
        xb, WinT, b_in, nullptr, nullptr, nullptr, nullptr, xzb, 4096, 1024, 16);
    // xact = silu(causal_conv(xzb[:, :2048]))   (4 rows per thread)
    conv_silu<<<dim3(8192 / 4), blk, 0, stream>>>(xzb, cw, cb, xact);
    // dtbcT[192][8192] = [sigmoid(xact@W_dt+b) | xact@W_B+b | xact@W_C+b]^T  (BK=128)
    gemm_mfma<64, 64, 128, 2, 4, 4, 2><<<dim3(3 * 128), blk512, 0, stream>>>(
        xact, WdtbcT, b_dt, b_B, b_C, nullptr, nullptr, dtbcT, 192, 2048, 3);
    // yT[64][8192] = selective_scan(dt, B, C)
    scan_kernel<<<dim3(128), blk, 0, stream>>>(dtbcT, yT);
    // ynb = bf16(layernorm over channels)
    ln_kernel<<<dim3(64), blk, 0, stream>>>(yT, ynb);
    // hb = (ynb@W_si + b_si + D*xact) * sigmoid(gate)
    // NEW: 4-wave 128x128 (64x64 wave tiles, 4 blocks/CU)
    gemm_mfma<128, 128, 64, 2, 2, 4, 3><<<dim3(16 * 64), blk, 0, stream>>>(
        ynb, WsiT, b_si, Dv, nullptr, xzb + 2048, xact, hb, 2048, 64, 16);
    // out = hb @ W_out + b_out
    // NEW: 4-wave 128x128 (64x64 wave tiles, 4 blocks/CU), BK=64 conflict-free
    gemm_mfma<128, 128, 64, 2, 2, 4, 0><<<dim3(8 * 64), blk, 0, stream>>>(
        hb, WoutT, b_out, nullptr, nullptr, nullptr, nullptr, out, 1024, 2048, 8);
}